// Round 1
// baseline (311.980 us; speedup 1.0000x reference)
//
#include <hip/hip_runtime.h>
#include <cstdint>
#include <cstddef>

typedef __bf16 bf16x8 __attribute__((ext_vector_type(8)));
typedef float  f32x4  __attribute__((ext_vector_type(4)));
typedef unsigned short u16;

#define MFMA16(a, b, c) __builtin_amdgcn_mfma_f32_16x16x32_bf16((a), (b), (c), 0, 0, 0)
#define ASYNC16(g, l)                                                              \
  __builtin_amdgcn_global_load_lds(                                                \
      (const __attribute__((address_space(1))) unsigned int*)(g),                  \
      (__attribute__((address_space(3))) unsigned int*)(l), 16, 0, 0)

__device__ __forceinline__ u16 f2bf(float f) {
  unsigned u = __builtin_bit_cast(unsigned, f);
  u += 0x7fffu + ((u >> 16) & 1u);
  return (u16)(u >> 16);
}

#define SEQ 2048
#define CH  1024
#define NH  16
#define HD  64
// log2(e) / sqrt(64) folded into stored Q so softmax uses exp2
#define QSCALE 0.18033688011112042f

// ---------------- cast x (fp32 -> bf16), 4 elems/thread ----------------
__global__ void __launch_bounds__(256) cast_x_kernel(const float* __restrict__ in,
                                                     u16* __restrict__ out) {
  int i = blockIdx.x * 256 + threadIdx.x;
  float4 v = ((const float4*)in)[i];
  ushort4 o;
  o.x = f2bf(v.x); o.y = f2bf(v.y); o.z = f2bf(v.z); o.w = f2bf(v.w);
  ((ushort4*)out)[i] = o;
}

// ------------- transpose-cast weights: in (R x C) f32 -> out (C x R) bf16 -------------
__global__ void __launch_bounds__(256) tcast_kernel(const float* __restrict__ in,
                                                    u16* __restrict__ out, int R, int C) {
  __shared__ u16 t[64][68];
  int c0 = blockIdx.x * 64, r0 = blockIdx.y * 64;
  int tx = threadIdx.x;
  int rr = tx >> 6, cc = tx & 63;
#pragma unroll
  for (int i = 0; i < 16; ++i) {
    int r = i * 4 + rr;
    t[r][cc] = f2bf(in[(size_t)(r0 + r) * C + c0 + cc]);
  }
  __syncthreads();
#pragma unroll
  for (int i = 0; i < 16; ++i) {
    int r = i * 4 + rr;
    out[(size_t)(c0 + r) * R + r0 + cc] = t[cc][r];
  }
}

// ------------- transpose V slice of qkv (per b,h: (N x D) -> (D x N)) -------------
__global__ void __launch_bounds__(256) tv_kernel(const u16* __restrict__ qkv,
                                                 u16* __restrict__ vt) {
  __shared__ u16 t[64][68];
  int n0 = blockIdx.x * 64;
  int bh = blockIdx.y;
  int b = bh >> 4, h = bh & 15;
  int tx = threadIdx.x;
  int rr = tx >> 6, cc = tx & 63;
  const u16* src = qkv + (size_t)(b * SEQ) * 3072 + 2048 + h * 64;
#pragma unroll
  for (int i = 0; i < 16; ++i) {
    int n = i * 4 + rr;
    t[n][cc] = src[(size_t)(n0 + n) * 3072 + cc];
  }
  __syncthreads();
  u16* dst = vt + (size_t)bh * 64 * SEQ;
#pragma unroll
  for (int i = 0; i < 16; ++i) {
    int d = i * 4 + rr;
    dst[(size_t)d * SEQ + n0 + cc] = t[cc][d];
  }
}

// ------------- GEMM: C(MxN) = A(MxK,bf16) @ Bt(NxK,bf16)^T + bias -------------
// mode 0: write bf16, scale cols<1024 by QSCALE (qkv gemm).  mode 1: write fp32 (proj).
__global__ void __launch_bounds__(256) gemm_kernel(const u16* __restrict__ A,
                                                   const u16* __restrict__ Bt,
                                                   const float* __restrict__ bias,
                                                   u16* __restrict__ outb,
                                                   float* __restrict__ outf,
                                                   int N, int K, int mode) {
  __shared__ alignas(16) u16 As[128 * 32];
  __shared__ alignas(16) u16 Bs[128 * 32];
  int tid = threadIdx.x;
  int lane = tid & 63, wave = tid >> 6;
  int wm = wave >> 1, wn = wave & 1;
  int qr = lane & 15, quad = lane >> 4;
  size_t rowA = (size_t)blockIdx.y * 128;
  size_t rowB = (size_t)blockIdx.x * 128;
  int r0 = tid >> 2, c0 = (tid & 3) << 3;

  const u16* a0 = A + (rowA + r0) * K + c0;
  const u16* b0 = Bt + (rowB + r0) * K + c0;
  size_t step64 = (size_t)64 * K;
  u16* lA = &As[r0 * 32 + c0];
  u16* lB = &Bs[r0 * 32 + c0];

  f32x4 acc[4][4];
#pragma unroll
  for (int mt = 0; mt < 4; ++mt)
#pragma unroll
    for (int nt = 0; nt < 4; ++nt) acc[mt][nt] = (f32x4){0.f, 0.f, 0.f, 0.f};

  for (int k0 = 0; k0 < K; k0 += 32) {
    ASYNC16(a0 + k0, lA);
    ASYNC16(a0 + k0 + step64, lA + 64 * 32);
    ASYNC16(b0 + k0, lB);
    ASYNC16(b0 + k0 + step64, lB + 64 * 32);
    __syncthreads();
    bf16x8 af[4], bfr[4];
#pragma unroll
    for (int mt = 0; mt < 4; ++mt)
      af[mt] = *(const bf16x8*)&As[(wm * 64 + mt * 16 + qr) * 32 + quad * 8];
#pragma unroll
    for (int nt = 0; nt < 4; ++nt)
      bfr[nt] = *(const bf16x8*)&Bs[(wn * 64 + nt * 16 + qr) * 32 + quad * 8];
#pragma unroll
    for (int mt = 0; mt < 4; ++mt)
#pragma unroll
      for (int nt = 0; nt < 4; ++nt)
        acc[mt][nt] = MFMA16(af[mt], bfr[nt], acc[mt][nt]);
    __syncthreads();
  }

#pragma unroll
  for (int nt = 0; nt < 4; ++nt) {
    int col = (int)rowB + wn * 64 + nt * 16 + qr;
    float bv = bias[col];
#pragma unroll
    for (int mt = 0; mt < 4; ++mt) {
      size_t row = rowA + wm * 64 + mt * 16 + quad * 4;
#pragma unroll
      for (int r = 0; r < 4; ++r) {
        float v = acc[mt][nt][r] + bv;
        if (mode == 0) {
          if (col < 1024) v *= QSCALE;
          outb[(row + r) * N + col] = f2bf(v);
        } else {
          outf[(row + r) * N + col] = v;
        }
      }
    }
  }
}

// ------------- flash attention: 128 Q rows/block, 64-key tiles -------------
__global__ void __launch_bounds__(256) attn_kernel(const u16* __restrict__ qkv,
                                                   const u16* __restrict__ vt,
                                                   u16* __restrict__ out) {
  __shared__ alignas(16) u16 plds[4][32 * 64];
  int bh = blockIdx.x;
  int b = bh >> 4, h = bh & 15;
  int m0 = blockIdx.y * 128;
  int tid = threadIdx.x;
  int lane = tid & 63, wave = tid >> 6;
  int qr = lane & 15, quad = lane >> 4;

  const u16* qbase = qkv + (size_t)(b * SEQ + m0 + wave * 32) * 3072 + h * 64;
  bf16x8 qf[2][2];
#pragma unroll
  for (int mt = 0; mt < 2; ++mt)
#pragma unroll
    for (int ks = 0; ks < 2; ++ks)
      qf[mt][ks] = *(const bf16x8*)&qbase[(size_t)(mt * 16 + qr) * 3072 + ks * 32 + quad * 8];

  float mi[2][4], li[2][4];
  f32x4 o[2][4];
#pragma unroll
  for (int mt = 0; mt < 2; ++mt) {
#pragma unroll
    for (int r = 0; r < 4; ++r) { mi[mt][r] = -1e30f; li[mt][r] = 0.f; }
#pragma unroll
    for (int dt = 0; dt < 4; ++dt) o[mt][dt] = (f32x4){0.f, 0.f, 0.f, 0.f};
  }

  const u16* kbase = qkv + (size_t)(b * SEQ) * 3072 + 1024 + h * 64;
  const u16* vbase = vt + (size_t)bh * 64 * SEQ;
  u16* pw = &plds[wave][0];

  for (int n0 = 0; n0 < SEQ; n0 += 64) {
    bf16x8 kf[4][2];
#pragma unroll
    for (int nt = 0; nt < 4; ++nt)
#pragma unroll
      for (int ks = 0; ks < 2; ++ks)
        kf[nt][ks] =
            *(const bf16x8*)&kbase[(size_t)(n0 + nt * 16 + qr) * 3072 + ks * 32 + quad * 8];

    f32x4 s[2][4];
#pragma unroll
    for (int mt = 0; mt < 2; ++mt)
#pragma unroll
      for (int nt = 0; nt < 4; ++nt) {
        f32x4 z = (f32x4){0.f, 0.f, 0.f, 0.f};
        z = MFMA16(qf[mt][0], kf[nt][0], z);
        z = MFMA16(qf[mt][1], kf[nt][1], z);
        s[mt][nt] = z;
      }

#pragma unroll
    for (int mt = 0; mt < 2; ++mt) {
      float rmax[4], rsum[4];
#pragma unroll
      for (int r = 0; r < 4; ++r) {
        float m = fmaxf(fmaxf(s[mt][0][r], s[mt][1][r]), fmaxf(s[mt][2][r], s[mt][3][r]));
        rmax[r] = m;
      }
#pragma unroll
      for (int mask = 1; mask <= 8; mask <<= 1)
#pragma unroll
        for (int r = 0; r < 4; ++r)
          rmax[r] = fmaxf(rmax[r], __shfl_xor(rmax[r], mask, 64));
#pragma unroll
      for (int r = 0; r < 4; ++r) {
        float mn = fmaxf(mi[mt][r], rmax[r]);
        float alpha = exp2f(mi[mt][r] - mn);
        mi[mt][r] = mn;
        li[mt][r] *= alpha;
#pragma unroll
        for (int dt = 0; dt < 4; ++dt) o[mt][dt][r] *= alpha;
        rsum[r] = 0.f;
      }
#pragma unroll
      for (int nt = 0; nt < 4; ++nt)
#pragma unroll
        for (int r = 0; r < 4; ++r) {
          float p = exp2f(s[mt][nt][r] - mi[mt][r]);
          rsum[r] += p;
          pw[(mt * 16 + quad * 4 + r) * 64 + nt * 16 + qr] = f2bf(p);
        }
#pragma unroll
      for (int mask = 1; mask <= 8; mask <<= 1)
#pragma unroll
        for (int r = 0; r < 4; ++r) rsum[r] += __shfl_xor(rsum[r], mask, 64);
#pragma unroll
      for (int r = 0; r < 4; ++r) li[mt][r] += rsum[r];
    }

    bf16x8 vf[4][2];
#pragma unroll
    for (int dt = 0; dt < 4; ++dt)
#pragma unroll
      for (int ks = 0; ks < 2; ++ks)
        vf[dt][ks] =
            *(const bf16x8*)&vbase[(size_t)(dt * 16 + qr) * SEQ + n0 + ks * 32 + quad * 8];
    bf16x8 pf[2][2];
#pragma unroll
    for (int mt = 0; mt < 2; ++mt)
#pragma unroll
      for (int ks = 0; ks < 2; ++ks)
        pf[mt][ks] = *(const bf16x8*)&pw[(mt * 16 + qr) * 64 + ks * 32 + quad * 8];
#pragma unroll
    for (int mt = 0; mt < 2; ++mt)
#pragma unroll
      for (int dt = 0; dt < 4; ++dt) {
        o[mt][dt] = MFMA16(pf[mt][0], vf[dt][0], o[mt][dt]);
        o[mt][dt] = MFMA16(pf[mt][1], vf[dt][1], o[mt][dt]);
      }
  }

  u16* obase = out + (size_t)(b * SEQ + m0 + wave * 32) * CH + h * 64;
#pragma unroll
  for (int mt = 0; mt < 2; ++mt)
#pragma unroll
    for (int dt = 0; dt < 4; ++dt)
#pragma unroll
      for (int r = 0; r < 4; ++r) {
        float v = o[mt][dt][r] / li[mt][r];
        obase[(size_t)(mt * 16 + quad * 4 + r) * CH + dt * 16 + qr] = f2bf(v);
      }
}

extern "C" void kernel_launch(void* const* d_in, const int* in_sizes, int n_in,
                              void* d_out, int out_size, void* d_ws, size_t ws_size,
                              hipStream_t stream) {
  const float* x      = (const float*)d_in[0];
  const float* qkv_w  = (const float*)d_in[1];
  const float* qkv_b  = (const float*)d_in[2];
  const float* proj_w = (const float*)d_in[3];
  const float* proj_b = (const float*)d_in[4];
  float* out = (float*)d_out;

  char* w = (char*)d_ws;
  // ws layout (42 MB):
  //   qkv_bf : 4096x3072 bf16 = 25165824 B
  //   xb     : 4096x1024 bf16 =  8388608 B  (reused as attn_bf after gemm1)
  //   wprojt : 1024x1024 bf16 =  2097152 B
  //   wqkvt  : 3072x1024 bf16 (6 MB) region sized 8 MB, reused as vt (B,H,D,N)
  u16* qkv_bf = (u16*)w;
  u16* xb     = (u16*)(w + 25165824);
  u16* wprojt = (u16*)(w + 25165824 + 8388608);
  u16* wqkvt  = (u16*)(w + 25165824 + 8388608 + 2097152);
  u16* attn_bf = xb;
  u16* vt      = wqkvt;

  cast_x_kernel<<<4096, 256, 0, stream>>>(x, xb);
  tcast_kernel<<<dim3(48, 16), 256, 0, stream>>>(qkv_w, wqkvt, 1024, 3072);
  tcast_kernel<<<dim3(16, 16), 256, 0, stream>>>(proj_w, wprojt, 1024, 1024);
  // qkv = x @ qkv_w + b  (bf16 out; Q cols pre-scaled by log2e/8)
  gemm_kernel<<<dim3(24, 32), 256, 0, stream>>>(xb, wqkvt, qkv_b, qkv_bf, nullptr, 3072, 1024, 0);
  tv_kernel<<<dim3(32, 32), 256, 0, stream>>>(qkv_bf, vt);
  attn_kernel<<<dim3(32, 16), 256, 0, stream>>>(qkv_bf, vt, attn_bf);
  // out = attn @ proj_w + b (fp32)
  gemm_kernel<<<dim3(8, 32), 256, 0, stream>>>(attn_bf, wprojt, proj_b, nullptr, out, 1024, 1024, 1);
}

// Round 3
// 279.465 us; speedup vs baseline: 1.1163x; 1.1163x over previous
//
#include <hip/hip_runtime.h>
#include <cstdint>
#include <cstddef>

typedef __bf16 bf16x8 __attribute__((ext_vector_type(8)));
typedef float  f32x4  __attribute__((ext_vector_type(4)));
typedef unsigned short u16;

#define MFMA16(a, b, c) __builtin_amdgcn_mfma_f32_16x16x32_bf16((a), (b), (c), 0, 0, 0)
#define ASYNC16(g, l)                                                              \
  __builtin_amdgcn_global_load_lds(                                                \
      (const __attribute__((address_space(1))) unsigned int*)(g),                  \
      (__attribute__((address_space(3))) unsigned int*)(l), 16, 0, 0)

__device__ __forceinline__ u16 f2bf(float f) {
  unsigned u = __builtin_bit_cast(unsigned, f);
  u += 0x7fffu + ((u >> 16) & 1u);
  return (u16)(u >> 16);
}

#define SEQ 2048
#define CH  1024
#define NH  16
#define HD  64
// log2(e) / sqrt(64) folded into stored Q so softmax uses exp2
#define QSCALE 0.18033688011112042f

// ---------------- cast x (fp32 -> bf16), 4 elems/thread ----------------
__global__ void __launch_bounds__(256) cast_x_kernel(const float* __restrict__ in,
                                                     u16* __restrict__ out) {
  int i = blockIdx.x * 256 + threadIdx.x;
  float4 v = ((const float4*)in)[i];
  ushort4 o;
  o.x = f2bf(v.x); o.y = f2bf(v.y); o.z = f2bf(v.z); o.w = f2bf(v.w);
  ((ushort4*)out)[i] = o;
}

// ------------- transpose-cast weights: in (R x C) f32 -> out (C x R) bf16 -------------
__global__ void __launch_bounds__(256) tcast_kernel(const float* __restrict__ in,
                                                    u16* __restrict__ out, int R, int C) {
  __shared__ u16 t[64][68];
  int c0 = blockIdx.x * 64, r0 = blockIdx.y * 64;
  int tx = threadIdx.x;
  int rr = tx >> 6, cc = tx & 63;
#pragma unroll
  for (int i = 0; i < 16; ++i) {
    int r = i * 4 + rr;
    t[r][cc] = f2bf(in[(size_t)(r0 + r) * C + c0 + cc]);
  }
  __syncthreads();
#pragma unroll
  for (int i = 0; i < 16; ++i) {
    int r = i * 4 + rr;
    out[(size_t)(c0 + r) * R + r0 + cc] = t[cc][r];
  }
}

// ------------- transpose V slice of qkv (per b,h: (N x D) -> (D x N)) -------------
__global__ void __launch_bounds__(256) tv_kernel(const u16* __restrict__ qkv,
                                                 u16* __restrict__ vt) {
  __shared__ u16 t[64][68];
  int n0 = blockIdx.x * 64;
  int bh = blockIdx.y;
  int b = bh >> 4, h = bh & 15;
  int tx = threadIdx.x;
  int rr = tx >> 6, cc = tx & 63;
  const u16* src = qkv + (size_t)(b * SEQ) * 3072 + 2048 + h * 64;
#pragma unroll
  for (int i = 0; i < 16; ++i) {
    int n = i * 4 + rr;
    t[n][cc] = src[(size_t)(n0 + n) * 3072 + cc];
  }
  __syncthreads();
  u16* dst = vt + (size_t)bh * 64 * SEQ;
#pragma unroll
  for (int i = 0; i < 16; ++i) {
    int d = i * 4 + rr;
    dst[(size_t)d * SEQ + n0 + cc] = t[cc][d];
  }
}

// ------------- GEMM: C(MxN) = A(MxK,bf16) @ Bt(NxK,bf16)^T + bias -------------
// mode 0: write bf16, scale cols<1024 by QSCALE (qkv gemm).  mode 1: write fp32 (proj).
__global__ void __launch_bounds__(256) gemm_kernel(const u16* __restrict__ A,
                                                   const u16* __restrict__ Bt,
                                                   const float* __restrict__ bias,
                                                   u16* __restrict__ outb,
                                                   float* __restrict__ outf,
                                                   int N, int K, int mode) {
  __shared__ alignas(16) u16 As[128 * 32];
  __shared__ alignas(16) u16 Bs[128 * 32];
  int tid = threadIdx.x;
  int lane = tid & 63, wave = tid >> 6;
  int wm = wave >> 1, wn = wave & 1;
  int qr = lane & 15, quad = lane >> 4;
  size_t rowA = (size_t)blockIdx.y * 128;
  size_t rowB = (size_t)blockIdx.x * 128;
  int r0 = tid >> 2, c0 = (tid & 3) << 3;

  const u16* a0 = A + (rowA + r0) * K + c0;
  const u16* b0 = Bt + (rowB + r0) * K + c0;
  size_t step64 = (size_t)64 * K;
  u16* lA = &As[r0 * 32 + c0];
  u16* lB = &Bs[r0 * 32 + c0];

  f32x4 acc[4][4];
#pragma unroll
  for (int mt = 0; mt < 4; ++mt)
#pragma unroll
    for (int nt = 0; nt < 4; ++nt) acc[mt][nt] = (f32x4){0.f, 0.f, 0.f, 0.f};

  for (int k0 = 0; k0 < K; k0 += 32) {
    ASYNC16(a0 + k0, lA);
    ASYNC16(a0 + k0 + step64, lA + 64 * 32);
    ASYNC16(b0 + k0, lB);
    ASYNC16(b0 + k0 + step64, lB + 64 * 32);
    __syncthreads();
    bf16x8 af[4], bfr[4];
#pragma unroll
    for (int mt = 0; mt < 4; ++mt)
      af[mt] = *(const bf16x8*)&As[(wm * 64 + mt * 16 + qr) * 32 + quad * 8];
#pragma unroll
    for (int nt = 0; nt < 4; ++nt)
      bfr[nt] = *(const bf16x8*)&Bs[(wn * 64 + nt * 16 + qr) * 32 + quad * 8];
#pragma unroll
    for (int mt = 0; mt < 4; ++mt)
#pragma unroll
      for (int nt = 0; nt < 4; ++nt)
        acc[mt][nt] = MFMA16(af[mt], bfr[nt], acc[mt][nt]);
    __syncthreads();
  }

#pragma unroll
  for (int nt = 0; nt < 4; ++nt) {
    int col = (int)rowB + wn * 64 + nt * 16 + qr;
    float bv = bias[col];
#pragma unroll
    for (int mt = 0; mt < 4; ++mt) {
      size_t row = rowA + wm * 64 + mt * 16 + quad * 4;
#pragma unroll
      for (int r = 0; r < 4; ++r) {
        float v = acc[mt][nt][r] + bv;
        if (mode == 0) {
          if (col < 1024) v *= QSCALE;
          outb[(row + r) * N + col] = f2bf(v);
        } else {
          outf[(row + r) * N + col] = v;
        }
      }
    }
  }
}

// ------------- flash attention v2b: 32 Q rows/block, 4 waves split keys -------------
// No online max (scores bounded; exp2 has huge headroom); per-lane deferred sum.
// P buffer per wave: [32 rows][64] bf16, stride 64 shorts (128 B, keeps ds_read_b128
// 16B-aligned) with XOR chunk swizzle (col-chunk ^ row&7) for bank-conflict freedom.
__global__ void __launch_bounds__(256) attn_kernel(const u16* __restrict__ qkv,
                                                   const u16* __restrict__ vt,
                                                   u16* __restrict__ out) {
  // pool: P buffers 4*4096B = 16KB, overlaid later by og (32KB) + lg (512B)
  __shared__ alignas(16) char smem[33280];
  int bh = blockIdx.x;
  int b = bh >> 4, h = bh & 15;
  int m0 = blockIdx.y * 32;
  int tid = threadIdx.x;
  int lane = tid & 63, wave = tid >> 6;
  int qr = lane & 15, quad = lane >> 4;

  u16* pw = (u16*)(smem + wave * 4096);  // [32][64] bf16, swizzled
  float* og = (float*)smem;              // [4][32][64] f32
  float* lg = (float*)(smem + 32768);    // [4][32] f32

  const u16* qbase = qkv + (size_t)(b * SEQ + m0) * 3072 + h * 64;
  bf16x8 qf[2][2];
#pragma unroll
  for (int mt = 0; mt < 2; ++mt)
#pragma unroll
    for (int ks = 0; ks < 2; ++ks)
      qf[mt][ks] = *(const bf16x8*)&qbase[(size_t)(mt * 16 + qr) * 3072 + ks * 32 + quad * 8];

  f32x4 o[2][4];
  float rsum[2][4];
#pragma unroll
  for (int mt = 0; mt < 2; ++mt) {
#pragma unroll
    for (int r = 0; r < 4; ++r) rsum[mt][r] = 0.f;
#pragma unroll
    for (int dt = 0; dt < 4; ++dt) o[mt][dt] = (f32x4){0.f, 0.f, 0.f, 0.f};
  }

  const u16* kbase = qkv + (size_t)(b * SEQ) * 3072 + 1024 + h * 64;
  const u16* vbase = vt + (size_t)bh * 64 * SEQ;

  int n_begin = wave * 512;
  for (int n0 = n_begin; n0 < n_begin + 512; n0 += 64) {
    bf16x8 kf[4][2];
#pragma unroll
    for (int nt = 0; nt < 4; ++nt)
#pragma unroll
      for (int ks = 0; ks < 2; ++ks)
        kf[nt][ks] =
            *(const bf16x8*)&kbase[(size_t)(n0 + nt * 16 + qr) * 3072 + ks * 32 + quad * 8];

    f32x4 s[2][4];
#pragma unroll
    for (int mt = 0; mt < 2; ++mt)
#pragma unroll
      for (int nt = 0; nt < 4; ++nt) {
        f32x4 z = (f32x4){0.f, 0.f, 0.f, 0.f};
        z = MFMA16(qf[mt][0], kf[nt][0], z);
        z = MFMA16(qf[mt][1], kf[nt][1], z);
        s[mt][nt] = z;
      }

    // p = exp2(s); accumulate per-lane sums; write P (bf16) to wave-private LDS
    // swizzled store: elem (row,col) -> pw[row*64 + ((col>>3) ^ (row&7))*8 + (col&7)]
#pragma unroll
    for (int mt = 0; mt < 2; ++mt)
#pragma unroll
      for (int nt = 0; nt < 4; ++nt)
#pragma unroll
        for (int r = 0; r < 4; ++r) {
          float p = __builtin_amdgcn_exp2f(s[mt][nt][r]);
          rsum[mt][r] += p;
          int row = mt * 16 + quad * 4 + r;
          int col = nt * 16 + qr;
          pw[row * 64 + (((col >> 3) ^ (row & 7)) << 3) + (col & 7)] = f2bf(p);
        }

    bf16x8 vf[4][2];
#pragma unroll
    for (int dt = 0; dt < 4; ++dt)
#pragma unroll
      for (int ks = 0; ks < 2; ++ks)
        vf[dt][ks] =
            *(const bf16x8*)&vbase[(size_t)(dt * 16 + qr) * SEQ + n0 + ks * 32 + quad * 8];
    bf16x8 pf[2][2];
#pragma unroll
    for (int mt = 0; mt < 2; ++mt)
#pragma unroll
      for (int ks = 0; ks < 2; ++ks) {
        int row = mt * 16 + qr;
        int chunk = ks * 4 + quad;  // (ks*32 + quad*8) >> 3
        pf[mt][ks] = *(const bf16x8*)&pw[row * 64 + ((chunk ^ (row & 7)) << 3)];
      }
#pragma unroll
    for (int mt = 0; mt < 2; ++mt)
#pragma unroll
      for (int dt = 0; dt < 4; ++dt) {
        o[mt][dt] = MFMA16(pf[mt][0], vf[dt][0], o[mt][dt]);
        o[mt][dt] = MFMA16(pf[mt][1], vf[dt][1], o[mt][dt]);
      }
  }

  // reduce per-lane partial sums across the 16 lanes sharing a row (masks 1,2,4,8)
#pragma unroll
  for (int mask = 1; mask <= 8; mask <<= 1)
#pragma unroll
    for (int mt = 0; mt < 2; ++mt)
#pragma unroll
      for (int r = 0; r < 4; ++r) rsum[mt][r] += __shfl_xor(rsum[mt][r], mask, 64);

  __syncthreads();  // all waves done reading their P buffers; og overlays them

#pragma unroll
  for (int mt = 0; mt < 2; ++mt)
#pragma unroll
    for (int dt = 0; dt < 4; ++dt)
#pragma unroll
      for (int r = 0; r < 4; ++r)
        og[wave * 2048 + (mt * 16 + quad * 4 + r) * 64 + dt * 16 + qr] = o[mt][dt][r];
  if (qr == 0) {
#pragma unroll
    for (int mt = 0; mt < 2; ++mt)
#pragma unroll
      for (int r = 0; r < 4; ++r)
        lg[wave * 32 + mt * 16 + quad * 4 + r] = rsum[mt][r];
  }
  __syncthreads();

  // combine 4 wave partials; 512 float4s over 256 threads
  const float4* og4 = (const float4*)og;
#pragma unroll
  for (int i = 0; i < 2; ++i) {
    int idx = tid + i * 256;  // float4 index in [32 rows][16 groups]
    int row = idx >> 4;
    float4 a0 = og4[idx];
    float4 a1 = og4[512 + idx];
    float4 a2 = og4[1024 + idx];
    float4 a3 = og4[1536 + idx];
    float l = lg[row] + lg[32 + row] + lg[64 + row] + lg[96 + row];
    float inv = 1.0f / l;
    float4 v;
    v.x = (a0.x + a1.x + a2.x + a3.x) * inv;
    v.y = (a0.y + a1.y + a2.y + a3.y) * inv;
    v.z = (a0.z + a1.z + a2.z + a3.z) * inv;
    v.w = (a0.w + a1.w + a2.w + a3.w) * inv;
    ushort4 uo;
    uo.x = f2bf(v.x); uo.y = f2bf(v.y); uo.z = f2bf(v.z); uo.w = f2bf(v.w);
    size_t e = (size_t)(b * SEQ + m0 + row) * CH + h * 64 + (idx & 15) * 4;
    *(ushort4*)&out[e] = uo;
  }
}

extern "C" void kernel_launch(void* const* d_in, const int* in_sizes, int n_in,
                              void* d_out, int out_size, void* d_ws, size_t ws_size,
                              hipStream_t stream) {
  const float* x      = (const float*)d_in[0];
  const float* qkv_w  = (const float*)d_in[1];
  const float* qkv_b  = (const float*)d_in[2];
  const float* proj_w = (const float*)d_in[3];
  const float* proj_b = (const float*)d_in[4];
  float* out = (float*)d_out;

  char* w = (char*)d_ws;
  // ws layout (42 MB):
  //   qkv_bf : 4096x3072 bf16 = 25165824 B
  //   xb     : 4096x1024 bf16 =  8388608 B  (reused as attn_bf after gemm1)
  //   wprojt : 1024x1024 bf16 =  2097152 B
  //   wqkvt  : 3072x1024 bf16 (6 MB) region sized 8 MB, reused as vt (B,H,D,N)
  u16* qkv_bf = (u16*)w;
  u16* xb     = (u16*)(w + 25165824);
  u16* wprojt = (u16*)(w + 25165824 + 8388608);
  u16* wqkvt  = (u16*)(w + 25165824 + 8388608 + 2097152);
  u16* attn_bf = xb;
  u16* vt      = wqkvt;

  cast_x_kernel<<<4096, 256, 0, stream>>>(x, xb);
  tcast_kernel<<<dim3(48, 16), 256, 0, stream>>>(qkv_w, wqkvt, 1024, 3072);
  tcast_kernel<<<dim3(16, 16), 256, 0, stream>>>(proj_w, wprojt, 1024, 1024);
  // qkv = x @ qkv_w + b  (bf16 out; Q cols pre-scaled by log2e/8)
  gemm_kernel<<<dim3(24, 32), 256, 0, stream>>>(xb, wqkvt, qkv_b, qkv_bf, nullptr, 3072, 1024, 0);
  tv_kernel<<<dim3(32, 32), 256, 0, stream>>>(qkv_bf, vt);
  attn_kernel<<<dim3(32, 64), 256, 0, stream>>>(qkv_bf, vt, attn_bf);
  // out = attn @ proj_w + b (fp32)
  gemm_kernel<<<dim3(8, 32), 256, 0, stream>>>(attn_bf, wprojt, proj_b, nullptr, out, 1024, 1024, 1);
}

// Round 4
// 225.021 us; speedup vs baseline: 1.3864x; 1.2419x over previous
//
#include <hip/hip_runtime.h>
#include <cstdint>
#include <cstddef>

typedef __bf16 bf16x8 __attribute__((ext_vector_type(8)));
typedef float  f32x4  __attribute__((ext_vector_type(4)));
typedef unsigned short u16;

#define MFMA16(a, b, c) __builtin_amdgcn_mfma_f32_16x16x32_bf16((a), (b), (c), 0, 0, 0)
#define ASYNC16(g, l)                                                              \
  __builtin_amdgcn_global_load_lds(                                                \
      (const __attribute__((address_space(1))) unsigned int*)(g),                  \
      (__attribute__((address_space(3))) unsigned int*)(l), 16, 0, 0)

__device__ __forceinline__ u16 f2bf(float f) {
  unsigned u = __builtin_bit_cast(unsigned, f);
  u += 0x7fffu + ((u >> 16) & 1u);
  return (u16)(u >> 16);
}

#define SEQ 2048
#define CH  1024
#define NH  16
#define HD  64
// log2(e) / sqrt(64) folded into stored Q so softmax uses exp2
#define QSCALE 0.18033688011112042f

// ---------------- cast x (fp32 -> bf16), 4 elems/thread ----------------
__global__ void __launch_bounds__(256) cast_x_kernel(const float* __restrict__ in,
                                                     u16* __restrict__ out) {
  int i = blockIdx.x * 256 + threadIdx.x;
  float4 v = ((const float4*)in)[i];
  ushort4 o;
  o.x = f2bf(v.x); o.y = f2bf(v.y); o.z = f2bf(v.z); o.w = f2bf(v.w);
  ((ushort4*)out)[i] = o;
}

// ------------- transpose-cast weights: in (R x C) f32 -> out (C x R) bf16 -------------
__global__ void __launch_bounds__(256) tcast_kernel(const float* __restrict__ in,
                                                    u16* __restrict__ out, int R, int C) {
  __shared__ u16 t[64][68];
  int c0 = blockIdx.x * 64, r0 = blockIdx.y * 64;
  int tx = threadIdx.x;
  int rr = tx >> 6, cc = tx & 63;
#pragma unroll
  for (int i = 0; i < 16; ++i) {
    int r = i * 4 + rr;
    t[r][cc] = f2bf(in[(size_t)(r0 + r) * C + c0 + cc]);
  }
  __syncthreads();
#pragma unroll
  for (int i = 0; i < 16; ++i) {
    int r = i * 4 + rr;
    out[(size_t)(c0 + r) * R + r0 + cc] = t[cc][r];
  }
}

// ------------- transpose V slice of qkv (per b,h: (N x D) -> (D x N)) -------------
__global__ void __launch_bounds__(256) tv_kernel(const u16* __restrict__ qkv,
                                                 u16* __restrict__ vt) {
  __shared__ u16 t[64][68];
  int n0 = blockIdx.x * 64;
  int bh = blockIdx.y;
  int b = bh >> 4, h = bh & 15;
  int tx = threadIdx.x;
  int rr = tx >> 6, cc = tx & 63;
  const u16* src = qkv + (size_t)(b * SEQ) * 3072 + 2048 + h * 64;
#pragma unroll
  for (int i = 0; i < 16; ++i) {
    int n = i * 4 + rr;
    t[n][cc] = src[(size_t)(n0 + n) * 3072 + cc];
  }
  __syncthreads();
  u16* dst = vt + (size_t)bh * 64 * SEQ;
#pragma unroll
  for (int i = 0; i < 16; ++i) {
    int d = i * 4 + rr;
    dst[(size_t)d * SEQ + n0 + cc] = t[cc][d];
  }
}

// ------------- GEMM: C(MxN) = A(MxK,bf16) @ Bt(NxK,bf16)^T + bias -------------
// mode 0: write bf16, scale cols<1024 by QSCALE (qkv gemm).  mode 1: write fp32 (proj).
__global__ void __launch_bounds__(256) gemm_kernel(const u16* __restrict__ A,
                                                   const u16* __restrict__ Bt,
                                                   const float* __restrict__ bias,
                                                   u16* __restrict__ outb,
                                                   float* __restrict__ outf,
                                                   int N, int K, int mode) {
  __shared__ alignas(16) u16 As[128 * 32];
  __shared__ alignas(16) u16 Bs[128 * 32];
  int tid = threadIdx.x;
  int lane = tid & 63, wave = tid >> 6;
  int wm = wave >> 1, wn = wave & 1;
  int qr = lane & 15, quad = lane >> 4;
  size_t rowA = (size_t)blockIdx.y * 128;
  size_t rowB = (size_t)blockIdx.x * 128;
  int r0 = tid >> 2, c0 = (tid & 3) << 3;

  const u16* a0 = A + (rowA + r0) * K + c0;
  const u16* b0 = Bt + (rowB + r0) * K + c0;
  size_t step64 = (size_t)64 * K;
  u16* lA = &As[r0 * 32 + c0];
  u16* lB = &Bs[r0 * 32 + c0];

  f32x4 acc[4][4];
#pragma unroll
  for (int mt = 0; mt < 4; ++mt)
#pragma unroll
    for (int nt = 0; nt < 4; ++nt) acc[mt][nt] = (f32x4){0.f, 0.f, 0.f, 0.f};

  for (int k0 = 0; k0 < K; k0 += 32) {
    ASYNC16(a0 + k0, lA);
    ASYNC16(a0 + k0 + step64, lA + 64 * 32);
    ASYNC16(b0 + k0, lB);
    ASYNC16(b0 + k0 + step64, lB + 64 * 32);
    __syncthreads();
    bf16x8 af[4], bfr[4];
#pragma unroll
    for (int mt = 0; mt < 4; ++mt)
      af[mt] = *(const bf16x8*)&As[(wm * 64 + mt * 16 + qr) * 32 + quad * 8];
#pragma unroll
    for (int nt = 0; nt < 4; ++nt)
      bfr[nt] = *(const bf16x8*)&Bs[(wn * 64 + nt * 16 + qr) * 32 + quad * 8];
#pragma unroll
    for (int mt = 0; mt < 4; ++mt)
#pragma unroll
      for (int nt = 0; nt < 4; ++nt)
        acc[mt][nt] = MFMA16(af[mt], bfr[nt], acc[mt][nt]);
    __syncthreads();
  }

#pragma unroll
  for (int nt = 0; nt < 4; ++nt) {
    int col = (int)rowB + wn * 64 + nt * 16 + qr;
    float bv = bias[col];
#pragma unroll
    for (int mt = 0; mt < 4; ++mt) {
      size_t row = rowA + wm * 64 + mt * 16 + quad * 4;
#pragma unroll
      for (int r = 0; r < 4; ++r) {
        float v = acc[mt][nt][r] + bv;
        if (mode == 0) {
          if (col < 1024) v *= QSCALE;
          outb[(row + r) * N + col] = f2bf(v);
        } else {
          outf[(row + r) * N + col] = v;
        }
      }
    }
  }
}

// ------------- flash attention v3: LDS-staged K/V, double-buffered -------------
// 4 waves x 32 Q rows = 128 rows/block; each wave walks all 32 key tiles (64 keys).
// K-tile and Vt-tile DMA'd to LDS via global_load_lds (16B), 1 barrier/tile.
// Staged rows are chunk-XOR-swizzled (global source side) for conflict-free b128 reads.
// No online max (scores bounded); per-lane deferred denominator; P per-wave in LDS.
__global__ void __launch_bounds__(256) attn_kernel(const u16* __restrict__ qkv,
                                                   const u16* __restrict__ vt,
                                                   u16* __restrict__ out) {
  __shared__ alignas(16) u16 kbuf[2][64 * 64];
  __shared__ alignas(16) u16 vbuf[2][64 * 64];
  __shared__ alignas(16) u16 pbuf[4][32 * 64];
  int bh = blockIdx.x;
  int b = bh >> 4, h = bh & 15;
  int m0 = blockIdx.y * 128;
  int tid = threadIdx.x;
  int lane = tid & 63, wave = tid >> 6;
  int qr = lane & 15, quad = lane >> 4;

  const u16* kbase = qkv + (size_t)(b * SEQ) * 3072 + 1024 + h * 64;   // K rows, stride 3072
  const u16* vtbase = vt + (size_t)bh * 64 * SEQ;                      // Vt rows, stride 2048
  u16* pw = &pbuf[wave][0];

  // per-lane staging constants: this wave stages rows [wave*16, wave*16+16)
  int srow0 = wave * 16 + (lane >> 3);   // +0 / +8 for the two insts
  int scs0 = (lane & 7) ^ (srow0 & 7);   // row parity bit3 differs between insts:
  int srow1 = srow0 + 8;
  int scs1 = (lane & 7) ^ (srow1 & 7);

  // ---- load Q fragments (once) ----
  const u16* qbase = qkv + (size_t)(b * SEQ + m0 + wave * 32) * 3072 + h * 64;
  bf16x8 qf[2][2];
#pragma unroll
  for (int mt = 0; mt < 2; ++mt)
#pragma unroll
    for (int ks = 0; ks < 2; ++ks)
      qf[mt][ks] = *(const bf16x8*)&qbase[(size_t)(mt * 16 + qr) * 3072 + ks * 32 + quad * 8];

  f32x4 o[2][4];
  float rsum[2][4];
#pragma unroll
  for (int mt = 0; mt < 2; ++mt) {
#pragma unroll
    for (int r = 0; r < 4; ++r) rsum[mt][r] = 0.f;
#pragma unroll
    for (int dt = 0; dt < 4; ++dt) o[mt][dt] = (f32x4){0.f, 0.f, 0.f, 0.f};
  }

  // ---- prologue: stage tile 0 into buffer 0 ----
  {
    const u16* kn = kbase;               // n0 = 0
    const u16* vn = vtbase;
    ASYNC16(kn + (size_t)srow0 * 3072 + scs0 * 8, &kbuf[0][wave * 1024 + lane * 8]);
    ASYNC16(kn + (size_t)srow1 * 3072 + scs1 * 8, &kbuf[0][wave * 1024 + 512 + lane * 8]);
    ASYNC16(vn + (size_t)srow0 * 2048 + scs0 * 8, &vbuf[0][wave * 1024 + lane * 8]);
    ASYNC16(vn + (size_t)srow1 * 2048 + scs1 * 8, &vbuf[0][wave * 1024 + 512 + lane * 8]);
  }

  for (int t = 0; t < 32; ++t) {
    int cur = t & 1;
    __syncthreads();  // staging of buf[cur] complete (vmcnt drained per wave at barrier)

    if (t + 1 < 32) {
      int nx = (t + 1) * 64;
      int o2 = cur ^ 1;
      const u16* kn = kbase + nx;        // K: cols advance? no — rows advance: kbase + row*3072; n0 means row offset
      // NOTE: key index is the ROW of K (stride 3072) and the COLUMN of Vt (stride 1)
      ASYNC16(kbase + (size_t)(nx + srow0) * 3072 + scs0 * 8, &kbuf[o2][wave * 1024 + lane * 8]);
      ASYNC16(kbase + (size_t)(nx + srow1) * 3072 + scs1 * 8, &kbuf[o2][wave * 1024 + 512 + lane * 8]);
      ASYNC16(vtbase + (size_t)srow0 * 2048 + nx + scs0 * 8, &vbuf[o2][wave * 1024 + lane * 8]);
      ASYNC16(vtbase + (size_t)srow1 * 2048 + nx + scs1 * 8, &vbuf[o2][wave * 1024 + 512 + lane * 8]);
      (void)kn;
    }

    const u16* kb = &kbuf[cur][0];
    const u16* vb = &vbuf[cur][0];

    // ---- kf fragments from LDS (swizzled chunks) ----
    bf16x8 kf[4][2];
#pragma unroll
    for (int nt = 0; nt < 4; ++nt)
#pragma unroll
      for (int ks = 0; ks < 2; ++ks)
        kf[nt][ks] = *(const bf16x8*)&kb[(nt * 16 + qr) * 64 + (((ks * 4 + quad) ^ (qr & 7)) << 3)];

    f32x4 s[2][4];
#pragma unroll
    for (int mt = 0; mt < 2; ++mt)
#pragma unroll
      for (int nt = 0; nt < 4; ++nt) {
        f32x4 z = (f32x4){0.f, 0.f, 0.f, 0.f};
        z = MFMA16(qf[mt][0], kf[nt][0], z);
        z = MFMA16(qf[mt][1], kf[nt][1], z);
        s[mt][nt] = z;
      }

    // p = exp2(s); per-lane sums; write P (bf16) to wave-private swizzled LDS
#pragma unroll
    for (int mt = 0; mt < 2; ++mt)
#pragma unroll
      for (int nt = 0; nt < 4; ++nt)
#pragma unroll
        for (int r = 0; r < 4; ++r) {
          float p = __builtin_amdgcn_exp2f(s[mt][nt][r]);
          rsum[mt][r] += p;
          int row = mt * 16 + quad * 4 + r;
          int col = nt * 16 + qr;
          pw[row * 64 + (((col >> 3) ^ (row & 7)) << 3) + (col & 7)] = f2bf(p);
        }

    // ---- vf fragments from LDS (swizzled chunks) ----
    bf16x8 vf[4][2];
#pragma unroll
    for (int dt = 0; dt < 4; ++dt)
#pragma unroll
      for (int ks = 0; ks < 2; ++ks)
        vf[dt][ks] = *(const bf16x8*)&vb[(dt * 16 + qr) * 64 + (((ks * 4 + quad) ^ (qr & 7)) << 3)];

    bf16x8 pf[2][2];
#pragma unroll
    for (int mt = 0; mt < 2; ++mt)
#pragma unroll
      for (int ks = 0; ks < 2; ++ks) {
        int row = mt * 16 + qr;
        int chunk = ks * 4 + quad;
        pf[mt][ks] = *(const bf16x8*)&pw[row * 64 + ((chunk ^ (row & 7)) << 3)];
      }
#pragma unroll
    for (int mt = 0; mt < 2; ++mt)
#pragma unroll
      for (int dt = 0; dt < 4; ++dt) {
        o[mt][dt] = MFMA16(pf[mt][0], vf[dt][0], o[mt][dt]);
        o[mt][dt] = MFMA16(pf[mt][1], vf[dt][1], o[mt][dt]);
      }
  }

  // reduce per-lane partial sums across the 16 lanes sharing a row (masks 1,2,4,8)
#pragma unroll
  for (int mask = 1; mask <= 8; mask <<= 1)
#pragma unroll
    for (int mt = 0; mt < 2; ++mt)
#pragma unroll
      for (int r = 0; r < 4; ++r) rsum[mt][r] += __shfl_xor(rsum[mt][r], mask, 64);

  // direct store: this wave owns rows [m0+wave*32, +32) entirely
  u16* obase = out + (size_t)(b * SEQ + m0 + wave * 32) * CH + h * 64;
#pragma unroll
  for (int mt = 0; mt < 2; ++mt)
#pragma unroll
    for (int r = 0; r < 4; ++r) {
      float inv = 1.0f / rsum[mt][r];
#pragma unroll
      for (int dt = 0; dt < 4; ++dt)
        obase[(size_t)(mt * 16 + quad * 4 + r) * CH + dt * 16 + qr] = f2bf(o[mt][dt][r] * inv);
    }
}

extern "C" void kernel_launch(void* const* d_in, const int* in_sizes, int n_in,
                              void* d_out, int out_size, void* d_ws, size_t ws_size,
                              hipStream_t stream) {
  const float* x      = (const float*)d_in[0];
  const float* qkv_w  = (const float*)d_in[1];
  const float* qkv_b  = (const float*)d_in[2];
  const float* proj_w = (const float*)d_in[3];
  const float* proj_b = (const float*)d_in[4];
  float* out = (float*)d_out;

  char* w = (char*)d_ws;
  // ws layout (42 MB):
  //   qkv_bf : 4096x3072 bf16 = 25165824 B
  //   xb     : 4096x1024 bf16 =  8388608 B  (reused as attn_bf after gemm1)
  //   wprojt : 1024x1024 bf16 =  2097152 B
  //   wqkvt  : 3072x1024 bf16 (6 MB) region sized 8 MB, reused as vt (B,H,D,N)
  u16* qkv_bf = (u16*)w;
  u16* xb     = (u16*)(w + 25165824);
  u16* wprojt = (u16*)(w + 25165824 + 8388608);
  u16* wqkvt  = (u16*)(w + 25165824 + 8388608 + 2097152);
  u16* attn_bf = xb;
  u16* vt      = wqkvt;

  cast_x_kernel<<<4096, 256, 0, stream>>>(x, xb);
  tcast_kernel<<<dim3(48, 16), 256, 0, stream>>>(qkv_w, wqkvt, 1024, 3072);
  tcast_kernel<<<dim3(16, 16), 256, 0, stream>>>(proj_w, wprojt, 1024, 1024);
  // qkv = x @ qkv_w + b  (bf16 out; Q cols pre-scaled by log2e/8)
  gemm_kernel<<<dim3(24, 32), 256, 0, stream>>>(xb, wqkvt, qkv_b, qkv_bf, nullptr, 3072, 1024, 0);
  tv_kernel<<<dim3(32, 32), 256, 0, stream>>>(qkv_bf, vt);
  attn_kernel<<<dim3(32, 16), 256, 0, stream>>>(qkv_bf, vt, attn_bf);
  // out = attn @ proj_w + b (fp32)
  gemm_kernel<<<dim3(8, 32), 256, 0, stream>>>(attn_bf, wprojt, proj_b, nullptr, out, 1024, 1024, 1);
}

// Round 6
// 219.464 us; speedup vs baseline: 1.4216x; 1.0253x over previous
//
#include <hip/hip_runtime.h>
#include <cstdint>
#include <cstddef>

typedef __bf16 bf16x8 __attribute__((ext_vector_type(8)));
typedef float  f32x4  __attribute__((ext_vector_type(4)));
typedef unsigned short u16;
typedef unsigned int u32;

#define MFMA16(a, b, c) __builtin_amdgcn_mfma_f32_16x16x32_bf16((a), (b), (c), 0, 0, 0)
#define ASYNC16(g, l)                                                              \
  __builtin_amdgcn_global_load_lds(                                                \
      (const __attribute__((address_space(1))) unsigned int*)(g),                  \
      (__attribute__((address_space(3))) unsigned int*)(l), 16, 0, 0)

__device__ __forceinline__ u16 f2bf(float f) {
  unsigned u = __builtin_bit_cast(unsigned, f);
  u += 0x7fffu + ((u >> 16) & 1u);
  return (u16)(u >> 16);
}

__device__ __forceinline__ u32 pack_bf2(float a, float b) {
  return (u32)f2bf(a) | ((u32)f2bf(b) << 16);
}

#define SEQ 2048
#define CH  1024
#define NH  16
#define HD  64
// log2(e) / sqrt(64) folded into stored Q so softmax uses exp2
#define QSCALE 0.18033688011112042f

// ---------------- cast x (fp32 -> bf16), 4 elems/thread ----------------
__global__ void __launch_bounds__(256) cast_x_kernel(const float* __restrict__ in,
                                                     u16* __restrict__ out) {
  int i = blockIdx.x * 256 + threadIdx.x;
  float4 v = ((const float4*)in)[i];
  ushort4 o;
  o.x = f2bf(v.x); o.y = f2bf(v.y); o.z = f2bf(v.z); o.w = f2bf(v.w);
  ((ushort4*)out)[i] = o;
}

// ------------- transpose-cast weights: in (R x C) f32 -> out (C x R) bf16 -------------
__global__ void __launch_bounds__(256) tcast_kernel(const float* __restrict__ in,
                                                    u16* __restrict__ out, int R, int C) {
  __shared__ u16 t[64][68];
  int c0 = blockIdx.x * 64, r0 = blockIdx.y * 64;
  int tx = threadIdx.x;
  int rr = tx >> 6, cc = tx & 63;
#pragma unroll
  for (int i = 0; i < 16; ++i) {
    int r = i * 4 + rr;
    t[r][cc] = f2bf(in[(size_t)(r0 + r) * C + c0 + cc]);
  }
  __syncthreads();
#pragma unroll
  for (int i = 0; i < 16; ++i) {
    int r = i * 4 + rr;
    out[(size_t)(c0 + r) * R + r0 + cc] = t[cc][r];
  }
}

// ------------- transpose V slice of qkv (per b,h: (N x D) -> (D x N)) -------------
__global__ void __launch_bounds__(256) tv_kernel(const u16* __restrict__ qkv,
                                                 u16* __restrict__ vt) {
  __shared__ u16 t[64][68];
  int n0 = blockIdx.x * 64;
  int bh = blockIdx.y;
  int b = bh >> 4, h = bh & 15;
  int tx = threadIdx.x;
  int rr = tx >> 6, cc = tx & 63;
  const u16* src = qkv + (size_t)(b * SEQ) * 3072 + 2048 + h * 64;
#pragma unroll
  for (int i = 0; i < 16; ++i) {
    int n = i * 4 + rr;
    t[n][cc] = src[(size_t)(n0 + n) * 3072 + cc];
  }
  __syncthreads();
  u16* dst = vt + (size_t)bh * 64 * SEQ;
#pragma unroll
  for (int i = 0; i < 16; ++i) {
    int d = i * 4 + rr;
    dst[(size_t)d * SEQ + n0 + cc] = t[cc][d];
  }
}

// ------------- GEMM: C(MxN) = A(MxK,bf16) @ Bt(NxK,bf16)^T + bias -------------
// mode 0: write bf16, scale cols<1024 by QSCALE (qkv gemm).  mode 1: write fp32 (proj).
__global__ void __launch_bounds__(256) gemm_kernel(const u16* __restrict__ A,
                                                   const u16* __restrict__ Bt,
                                                   const float* __restrict__ bias,
                                                   u16* __restrict__ outb,
                                                   float* __restrict__ outf,
                                                   int N, int K, int mode) {
  __shared__ alignas(16) u16 As[128 * 32];
  __shared__ alignas(16) u16 Bs[128 * 32];
  int tid = threadIdx.x;
  int lane = tid & 63, wave = tid >> 6;
  int wm = wave >> 1, wn = wave & 1;
  int qr = lane & 15, quad = lane >> 4;
  size_t rowA = (size_t)blockIdx.y * 128;
  size_t rowB = (size_t)blockIdx.x * 128;
  int r0 = tid >> 2, c0 = (tid & 3) << 3;

  const u16* a0 = A + (rowA + r0) * K + c0;
  const u16* b0 = Bt + (rowB + r0) * K + c0;
  size_t step64 = (size_t)64 * K;
  u16* lA = &As[r0 * 32 + c0];
  u16* lB = &Bs[r0 * 32 + c0];

  f32x4 acc[4][4];
#pragma unroll
  for (int mt = 0; mt < 4; ++mt)
#pragma unroll
    for (int nt = 0; nt < 4; ++nt) acc[mt][nt] = (f32x4){0.f, 0.f, 0.f, 0.f};

  for (int k0 = 0; k0 < K; k0 += 32) {
    ASYNC16(a0 + k0, lA);
    ASYNC16(a0 + k0 + step64, lA + 64 * 32);
    ASYNC16(b0 + k0, lB);
    ASYNC16(b0 + k0 + step64, lB + 64 * 32);
    __syncthreads();
    bf16x8 af[4], bfr[4];
#pragma unroll
    for (int mt = 0; mt < 4; ++mt)
      af[mt] = *(const bf16x8*)&As[(wm * 64 + mt * 16 + qr) * 32 + quad * 8];
#pragma unroll
    for (int nt = 0; nt < 4; ++nt)
      bfr[nt] = *(const bf16x8*)&Bs[(wn * 64 + nt * 16 + qr) * 32 + quad * 8];
#pragma unroll
    for (int mt = 0; mt < 4; ++mt)
#pragma unroll
      for (int nt = 0; nt < 4; ++nt)
        acc[mt][nt] = MFMA16(af[mt], bfr[nt], acc[mt][nt]);
    __syncthreads();
  }

#pragma unroll
  for (int nt = 0; nt < 4; ++nt) {
    int col = (int)rowB + wn * 64 + nt * 16 + qr;
    float bv = bias[col];
#pragma unroll
    for (int mt = 0; mt < 4; ++mt) {
      size_t row = rowA + wm * 64 + mt * 16 + quad * 4;
#pragma unroll
      for (int r = 0; r < 4; ++r) {
        float v = acc[mt][nt][r] + bv;
        if (mode == 0) {
          if (col < 1024) v *= QSCALE;
          outb[(row + r) * N + col] = f2bf(v);
        } else {
          outf[(row + r) * N + col] = v;
        }
      }
    }
  }
}

// ------------- flash attention v4: 64 Q rows/block, 4 waves x 16 rows -------------
// LDS-staged K/V double-buffered (global_load_lds 16B, chunk-XOR swizzle).
// QK^T computed TRANSPOSED (A=K, B=Q) so each lane holds 4 consecutive key-scores
// of one Q row -> packed cvt + single ds_write_b64 per 16-key tile.
// No online max (scores bounded); per-lane deferred denominator.
__global__ void __launch_bounds__(256) attn_kernel(const u16* __restrict__ qkv,
                                                   const u16* __restrict__ vt,
                                                   u16* __restrict__ out) {
  __shared__ alignas(16) u16 kbuf[2][64 * 64];
  __shared__ alignas(16) u16 vbuf[2][64 * 64];
  __shared__ alignas(16) u16 pbuf[4][16 * 64];
  int bh = blockIdx.x;
  int b = bh >> 4, h = bh & 15;
  int m0 = blockIdx.y * 64;
  int tid = threadIdx.x;
  int lane = tid & 63, wave = tid >> 6;
  int qr = lane & 15, quad = lane >> 4;

  const u16* kbase = qkv + (size_t)(b * SEQ) * 3072 + 1024 + h * 64;  // K rows, stride 3072
  const u16* vtbase = vt + (size_t)bh * 64 * SEQ;                     // Vt rows, stride 2048
  u16* pw = &pbuf[wave][0];

  // staging: this wave stages rows [wave*16, wave*16+16) of each tile
  int srow0 = wave * 16 + (lane >> 3);
  int scs0 = (lane & 7) ^ (srow0 & 7);
  int srow1 = srow0 + 8;
  int scs1 = (lane & 7) ^ (srow1 & 7);

  // ---- Q fragments (16 rows per wave) ----
  const u16* qbase = qkv + (size_t)(b * SEQ + m0 + wave * 16) * 3072 + h * 64;
  bf16x8 qf[2];
#pragma unroll
  for (int ks = 0; ks < 2; ++ks)
    qf[ks] = *(const bf16x8*)&qbase[(size_t)qr * 3072 + ks * 32 + quad * 8];

  f32x4 o[4];
  float rsum = 0.f;
#pragma unroll
  for (int dt = 0; dt < 4; ++dt) o[dt] = (f32x4){0.f, 0.f, 0.f, 0.f};

  // ---- prologue: stage tile 0 into buffer 0 ----
  ASYNC16(kbase + (size_t)srow0 * 3072 + scs0 * 8, &kbuf[0][wave * 1024 + lane * 8]);
  ASYNC16(kbase + (size_t)srow1 * 3072 + scs1 * 8, &kbuf[0][wave * 1024 + 512 + lane * 8]);
  ASYNC16(vtbase + (size_t)srow0 * 2048 + scs0 * 8, &vbuf[0][wave * 1024 + lane * 8]);
  ASYNC16(vtbase + (size_t)srow1 * 2048 + scs1 * 8, &vbuf[0][wave * 1024 + 512 + lane * 8]);

  for (int t = 0; t < 32; ++t) {
    int cur = t & 1;
    __syncthreads();  // staging of buf[cur] complete; prev reads of buf[cur^1] done

    if (t + 1 < 32) {
      int nx = (t + 1) * 64;
      int o2 = cur ^ 1;
      ASYNC16(kbase + (size_t)(nx + srow0) * 3072 + scs0 * 8, &kbuf[o2][wave * 1024 + lane * 8]);
      ASYNC16(kbase + (size_t)(nx + srow1) * 3072 + scs1 * 8, &kbuf[o2][wave * 1024 + 512 + lane * 8]);
      ASYNC16(vtbase + (size_t)srow0 * 2048 + nx + scs0 * 8, &vbuf[o2][wave * 1024 + lane * 8]);
      ASYNC16(vtbase + (size_t)srow1 * 2048 + nx + scs1 * 8, &vbuf[o2][wave * 1024 + 512 + lane * 8]);
    }

    const u16* kb = &kbuf[cur][0];
    const u16* vb = &vbuf[cur][0];

    // S^T = K.Q^T : D[n][m], lane: m = qr, n = nt*16 + quad*4 + r (4 consecutive keys)
    bf16x8 kf[4][2];
#pragma unroll
    for (int nt = 0; nt < 4; ++nt)
#pragma unroll
      for (int ks = 0; ks < 2; ++ks)
        kf[nt][ks] = *(const bf16x8*)&kb[(nt * 16 + qr) * 64 + (((ks * 4 + quad) ^ (qr & 7)) << 3)];

#pragma unroll
    for (int nt = 0; nt < 4; ++nt) {
      f32x4 z = (f32x4){0.f, 0.f, 0.f, 0.f};
      z = MFMA16(kf[nt][0], qf[0], z);
      z = MFMA16(kf[nt][1], qf[1], z);
      // p = exp2(s); accumulate per-lane denominator; packed-convert; one b64 write
      float p0 = __builtin_amdgcn_exp2f(z[0]);
      float p1 = __builtin_amdgcn_exp2f(z[1]);
      float p2 = __builtin_amdgcn_exp2f(z[2]);
      float p3 = __builtin_amdgcn_exp2f(z[3]);
      rsum += (p0 + p1) + (p2 + p3);
      uint2 pk;
      pk.x = pack_bf2(p0, p1);
      pk.y = pack_bf2(p2, p3);
      // P[m][n]: m=qr, n0 = nt*16 + quad*4 ; chunk-swizzled, 8B-aligned
      int nb = nt * 16 + quad * 4;
      int addr = qr * 64 + ((((nb >> 3) ^ (qr & 7)) << 3) | (nb & 7));
      *(uint2*)&pw[addr] = pk;
    }

    bf16x8 vf[4][2];
#pragma unroll
    for (int dt = 0; dt < 4; ++dt)
#pragma unroll
      for (int ks = 0; ks < 2; ++ks)
        vf[dt][ks] = *(const bf16x8*)&vb[(dt * 16 + qr) * 64 + (((ks * 4 + quad) ^ (qr & 7)) << 3)];

    bf16x8 pf[2];
#pragma unroll
    for (int ks = 0; ks < 2; ++ks)
      pf[ks] = *(const bf16x8*)&pw[qr * 64 + (((ks * 4 + quad) ^ (qr & 7)) << 3)];

#pragma unroll
    for (int dt = 0; dt < 4; ++dt) {
      o[dt] = MFMA16(pf[0], vf[dt][0], o[dt]);
      o[dt] = MFMA16(pf[1], vf[dt][1], o[dt]);
    }
  }

  // denominator: reduce the 4 lanes sharing a Q row (masks 16, 32)
  rsum += __shfl_xor(rsum, 16, 64);
  rsum += __shfl_xor(rsum, 32, 64);

  // output: o layout row m = quad*4+r, col d = qr. Fetch inv from lane qr==m.
  u16* obase = out + (size_t)(b * SEQ + m0 + wave * 16) * CH + h * 64;
#pragma unroll
  for (int r = 0; r < 4; ++r) {
    float l = __shfl(rsum, quad * 4 + r, 64);
    float inv = 1.0f / l;
#pragma unroll
    for (int dt = 0; dt < 4; ++dt)
      obase[(size_t)(quad * 4 + r) * CH + dt * 16 + qr] = f2bf(o[dt][r] * inv);
  }
}

extern "C" void kernel_launch(void* const* d_in, const int* in_sizes, int n_in,
                              void* d_out, int out_size, void* d_ws, size_t ws_size,
                              hipStream_t stream) {
  const float* x      = (const float*)d_in[0];
  const float* qkv_w  = (const float*)d_in[1];
  const float* qkv_b  = (const float*)d_in[2];
  const float* proj_w = (const float*)d_in[3];
  const float* proj_b = (const float*)d_in[4];
  float* out = (float*)d_out;

  char* w = (char*)d_ws;
  // ws layout (42 MB):
  //   qkv_bf : 4096x3072 bf16 = 25165824 B
  //   xb     : 4096x1024 bf16 =  8388608 B  (reused as attn_bf after gemm1)
  //   wprojt : 1024x1024 bf16 =  2097152 B
  //   wqkvt  : 3072x1024 bf16 (6 MB) region sized 8 MB, reused as vt (B,H,D,N)
  u16* qkv_bf = (u16*)w;
  u16* xb     = (u16*)(w + 25165824);
  u16* wprojt = (u16*)(w + 25165824 + 8388608);
  u16* wqkvt  = (u16*)(w + 25165824 + 8388608 + 2097152);
  u16* attn_bf = xb;
  u16* vt      = wqkvt;

  cast_x_kernel<<<4096, 256, 0, stream>>>(x, xb);
  tcast_kernel<<<dim3(48, 16), 256, 0, stream>>>(qkv_w, wqkvt, 1024, 3072);
  tcast_kernel<<<dim3(16, 16), 256, 0, stream>>>(proj_w, wprojt, 1024, 1024);
  // qkv = x @ qkv_w + b  (bf16 out; Q cols pre-scaled by log2e/8)
  gemm_kernel<<<dim3(24, 32), 256, 0, stream>>>(xb, wqkvt, qkv_b, qkv_bf, nullptr, 3072, 1024, 0);
  tv_kernel<<<dim3(32, 32), 256, 0, stream>>>(qkv_bf, vt);
  attn_kernel<<<dim3(32, 32), 256, 0, stream>>>(qkv_bf, vt, attn_bf);
  // out = attn @ proj_w + b (fp32)
  gemm_kernel<<<dim3(8, 32), 256, 0, stream>>>(attn_bf, wprojt, proj_b, nullptr, out, 1024, 1024, 1);
}

// Round 7
// 213.111 us; speedup vs baseline: 1.4639x; 1.0298x over previous
//
#include <hip/hip_runtime.h>
#include <cstdint>
#include <cstddef>

typedef __bf16 bf16x8 __attribute__((ext_vector_type(8)));
typedef __bf16 bf16x2v __attribute__((ext_vector_type(2)));
typedef unsigned short u16;
typedef u16 u16x8v __attribute__((ext_vector_type(8)));
typedef float  f32x4  __attribute__((ext_vector_type(4)));
typedef unsigned int u32;

#define MFMA16(a, b, c) __builtin_amdgcn_mfma_f32_16x16x32_bf16((a), (b), (c), 0, 0, 0)
#define ASYNC16(g, l)                                                              \
  __builtin_amdgcn_global_load_lds(                                                \
      (const __attribute__((address_space(1))) unsigned int*)(g),                  \
      (__attribute__((address_space(3))) unsigned int*)(l), 16, 0, 0)

__device__ __forceinline__ u16 f2bf(float f) {
  unsigned u = __builtin_bit_cast(unsigned, f);
  u += 0x7fffu + ((u >> 16) & 1u);
  return (u16)(u >> 16);
}

// packed fp32x2 -> bf16x2 (RNE) via hardware cvt
__device__ __forceinline__ u32 cvt2(float a, float b) {
  bf16x2v t;
  t[0] = (__bf16)a;
  t[1] = (__bf16)b;
  return __builtin_bit_cast(u32, t);
}

#define SEQ 2048
#define CH  1024
#define NH  16
#define HD  64
// log2(e) / sqrt(64) folded into stored Q so softmax uses exp2
#define QSCALE 0.18033688011112042f

// ---------------- cast x (fp32 -> bf16), 4 elems/thread ----------------
__global__ void __launch_bounds__(256) cast_x_kernel(const float* __restrict__ in,
                                                     u16* __restrict__ out) {
  int i = blockIdx.x * 256 + threadIdx.x;
  float4 v = ((const float4*)in)[i];
  ushort4 o;
  o.x = f2bf(v.x); o.y = f2bf(v.y); o.z = f2bf(v.z); o.w = f2bf(v.w);
  ((ushort4*)out)[i] = o;
}

// ------------- transpose-cast weights: in (R x C) f32 -> out (C x R) bf16 -------------
__global__ void __launch_bounds__(256) tcast_kernel(const float* __restrict__ in,
                                                    u16* __restrict__ out, int R, int C) {
  __shared__ u16 t[64][68];
  int c0 = blockIdx.x * 64, r0 = blockIdx.y * 64;
  int tx = threadIdx.x;
  int rr = tx >> 6, cc = tx & 63;
#pragma unroll
  for (int i = 0; i < 16; ++i) {
    int r = i * 4 + rr;
    t[r][cc] = f2bf(in[(size_t)(r0 + r) * C + c0 + cc]);
  }
  __syncthreads();
#pragma unroll
  for (int i = 0; i < 16; ++i) {
    int r = i * 4 + rr;
    out[(size_t)(c0 + r) * R + r0 + cc] = t[cc][r];
  }
}

// ------------- transpose V slice of qkv (per b,h: (N x D) -> (D x N)) -------------
__global__ void __launch_bounds__(256) tv_kernel(const u16* __restrict__ qkv,
                                                 u16* __restrict__ vt) {
  __shared__ u16 t[64][68];
  int n0 = blockIdx.x * 64;
  int bh = blockIdx.y;
  int b = bh >> 4, h = bh & 15;
  int tx = threadIdx.x;
  int rr = tx >> 6, cc = tx & 63;
  const u16* src = qkv + (size_t)(b * SEQ) * 3072 + 2048 + h * 64;
#pragma unroll
  for (int i = 0; i < 16; ++i) {
    int n = i * 4 + rr;
    t[n][cc] = src[(size_t)(n0 + n) * 3072 + cc];
  }
  __syncthreads();
  u16* dst = vt + (size_t)bh * 64 * SEQ;
#pragma unroll
  for (int i = 0; i < 16; ++i) {
    int d = i * 4 + rr;
    dst[(size_t)d * SEQ + n0 + cc] = t[cc][d];
  }
}

// ------------- GEMM: C(MxN) = A(MxK,bf16) @ Bt(NxK,bf16)^T + bias -------------
// Tile: (MT*32) x 128. MT=4 -> 128x128 (qkv gemm), MT=2 -> 64x128 (proj: more blocks).
// mode 0: write bf16, scale cols<1024 by QSCALE.  mode 1: write fp32.
template <int MT>
__global__ void __launch_bounds__(256) gemm_kernel(const u16* __restrict__ A,
                                                   const u16* __restrict__ Bt,
                                                   const float* __restrict__ bias,
                                                   u16* __restrict__ outb,
                                                   float* __restrict__ outf,
                                                   int N, int K, int mode) {
  constexpr int R = MT * 32;
  __shared__ alignas(16) u16 As[R * 32];
  __shared__ alignas(16) u16 Bs[128 * 32];
  int tid = threadIdx.x;
  int lane = tid & 63, wave = tid >> 6;
  int wm = wave >> 1, wn = wave & 1;
  int qr = lane & 15, quad = lane >> 4;
  size_t rowA = (size_t)blockIdx.y * R;
  size_t rowB = (size_t)blockIdx.x * 128;
  int r0 = tid >> 2, c0 = (tid & 3) << 3;

  const u16* a0 = A + (rowA + r0) * K + c0;
  const u16* b0 = Bt + (rowB + r0) * K + c0;
  size_t step64 = (size_t)64 * K;
  u16* lA = &As[r0 * 32 + c0];
  u16* lB = &Bs[r0 * 32 + c0];

  f32x4 acc[MT][4];
#pragma unroll
  for (int mt = 0; mt < MT; ++mt)
#pragma unroll
    for (int nt = 0; nt < 4; ++nt) acc[mt][nt] = (f32x4){0.f, 0.f, 0.f, 0.f};

  for (int k0 = 0; k0 < K; k0 += 32) {
#pragma unroll
    for (int i = 0; i < R / 64; ++i)
      ASYNC16(a0 + k0 + i * step64, lA + i * 64 * 32);
    ASYNC16(b0 + k0, lB);
    ASYNC16(b0 + k0 + step64, lB + 64 * 32);
    __syncthreads();
    bf16x8 af[MT], bfr[4];
#pragma unroll
    for (int mt = 0; mt < MT; ++mt)
      af[mt] = *(const bf16x8*)&As[(wm * (MT * 16) + mt * 16 + qr) * 32 + quad * 8];
#pragma unroll
    for (int nt = 0; nt < 4; ++nt)
      bfr[nt] = *(const bf16x8*)&Bs[(wn * 64 + nt * 16 + qr) * 32 + quad * 8];
#pragma unroll
    for (int mt = 0; mt < MT; ++mt)
#pragma unroll
      for (int nt = 0; nt < 4; ++nt)
        acc[mt][nt] = MFMA16(af[mt], bfr[nt], acc[mt][nt]);
    __syncthreads();
  }

#pragma unroll
  for (int nt = 0; nt < 4; ++nt) {
    int col = (int)rowB + wn * 64 + nt * 16 + qr;
    float bv = bias[col];
#pragma unroll
    for (int mt = 0; mt < MT; ++mt) {
      size_t row = rowA + wm * (MT * 16) + mt * 16 + quad * 4;
#pragma unroll
      for (int r = 0; r < 4; ++r) {
        float v = acc[mt][nt][r] + bv;
        if (mode == 0) {
          if (col < 1024) v *= QSCALE;
          outb[(row + r) * N + col] = f2bf(v);
        } else {
          outf[(row + r) * N + col] = v;
        }
      }
    }
  }
}

// ------------- flash attention v5: 128 Q rows/block, 4 waves x 32 rows -------------
// LDS-staged K/V double-buffered (global_load_lds 16B, chunk-XOR swizzle).
// QK^T computed transposed (A=K, B=Q): lane holds 4 consecutive key-scores of one
// Q row -> packed v_cvt + single ds_write_b64 per 16-key tile per mt.
// Denominator computed on the MFMA pipe via B=ones (no VALU adds, no shuffles).
__global__ void __launch_bounds__(256) attn_kernel(const u16* __restrict__ qkv,
                                                   const u16* __restrict__ vt,
                                                   u16* __restrict__ out) {
  __shared__ alignas(16) u16 kbuf[2][64 * 64];
  __shared__ alignas(16) u16 vbuf[2][64 * 64];
  __shared__ alignas(16) u16 pbuf[4][32 * 64];
  int bh = blockIdx.x;
  int b = bh >> 4, h = bh & 15;
  int m0 = blockIdx.y * 128;
  int tid = threadIdx.x;
  int lane = tid & 63, wave = tid >> 6;
  int qr = lane & 15, quad = lane >> 4;

  const u16* kbase = qkv + (size_t)(b * SEQ) * 3072 + 1024 + h * 64;  // K rows, stride 3072
  const u16* vtbase = vt + (size_t)bh * 64 * SEQ;                     // Vt rows, stride 2048
  u16* pw = &pbuf[wave][0];

  // staging: this wave stages rows [wave*16, wave*16+16) of each 64-row tile
  int srow0 = wave * 16 + (lane >> 3);
  int scs0 = (lane & 7) ^ (srow0 & 7);
  int srow1 = srow0 + 8;
  int scs1 = (lane & 7) ^ (srow1 & 7);

  // ---- Q fragments (32 rows per wave) ----
  const u16* qbase = qkv + (size_t)(b * SEQ + m0 + wave * 32) * 3072 + h * 64;
  bf16x8 qf[2][2];
#pragma unroll
  for (int mt = 0; mt < 2; ++mt)
#pragma unroll
    for (int ks = 0; ks < 2; ++ks)
      qf[mt][ks] = *(const bf16x8*)&qbase[(size_t)(mt * 16 + qr) * 3072 + ks * 32 + quad * 8];

  const bf16x8 vone = __builtin_bit_cast(bf16x8, (u16x8v)((u16)0x3F80));

  f32x4 o[2][4], l5[2];
#pragma unroll
  for (int mt = 0; mt < 2; ++mt) {
    l5[mt] = (f32x4){0.f, 0.f, 0.f, 0.f};
#pragma unroll
    for (int dt = 0; dt < 4; ++dt) o[mt][dt] = (f32x4){0.f, 0.f, 0.f, 0.f};
  }

  // ---- prologue: stage tile 0 into buffer 0 ----
  ASYNC16(kbase + (size_t)srow0 * 3072 + scs0 * 8, &kbuf[0][wave * 1024 + lane * 8]);
  ASYNC16(kbase + (size_t)srow1 * 3072 + scs1 * 8, &kbuf[0][wave * 1024 + 512 + lane * 8]);
  ASYNC16(vtbase + (size_t)srow0 * 2048 + scs0 * 8, &vbuf[0][wave * 1024 + lane * 8]);
  ASYNC16(vtbase + (size_t)srow1 * 2048 + scs1 * 8, &vbuf[0][wave * 1024 + 512 + lane * 8]);

  for (int t = 0; t < 32; ++t) {
    int cur = t & 1;
    __syncthreads();  // staging of buf[cur] complete; prev reads of buf[cur^1] done

    if (t + 1 < 32) {
      int nx = (t + 1) * 64;
      int o2 = cur ^ 1;
      ASYNC16(kbase + (size_t)(nx + srow0) * 3072 + scs0 * 8, &kbuf[o2][wave * 1024 + lane * 8]);
      ASYNC16(kbase + (size_t)(nx + srow1) * 3072 + scs1 * 8, &kbuf[o2][wave * 1024 + 512 + lane * 8]);
      ASYNC16(vtbase + (size_t)srow0 * 2048 + nx + scs0 * 8, &vbuf[o2][wave * 1024 + lane * 8]);
      ASYNC16(vtbase + (size_t)srow1 * 2048 + nx + scs1 * 8, &vbuf[o2][wave * 1024 + 512 + lane * 8]);
    }

    const u16* kb = &kbuf[cur][0];
    const u16* vb = &vbuf[cur][0];

    // S^T = K.Q^T : lane holds m = qr, n = nt*16 + quad*4 + r (4 consecutive keys)
    bf16x8 kf[4][2];
#pragma unroll
    for (int nt = 0; nt < 4; ++nt)
#pragma unroll
      for (int ks = 0; ks < 2; ++ks)
        kf[nt][ks] = *(const bf16x8*)&kb[(nt * 16 + qr) * 64 + (((ks * 4 + quad) ^ (qr & 7)) << 3)];

#pragma unroll
    for (int mt = 0; mt < 2; ++mt)
#pragma unroll
      for (int nt = 0; nt < 4; ++nt) {
        f32x4 z = (f32x4){0.f, 0.f, 0.f, 0.f};
        z = MFMA16(kf[nt][0], qf[mt][0], z);
        z = MFMA16(kf[nt][1], qf[mt][1], z);
        float p0 = __builtin_amdgcn_exp2f(z[0]);
        float p1 = __builtin_amdgcn_exp2f(z[1]);
        float p2 = __builtin_amdgcn_exp2f(z[2]);
        float p3 = __builtin_amdgcn_exp2f(z[3]);
        uint2 pk;
        pk.x = cvt2(p0, p1);
        pk.y = cvt2(p2, p3);
        // P[row=mt*16+qr][n]: chunk-swizzled, 8B-aligned
        int nb = nt * 16 + quad * 4;
        int addr = (mt * 16 + qr) * 64 + ((((nb >> 3) ^ (qr & 7)) << 3) | (nb & 7));
        *(uint2*)&pw[addr] = pk;
      }

    bf16x8 vf[4][2];
#pragma unroll
    for (int dt = 0; dt < 4; ++dt)
#pragma unroll
      for (int ks = 0; ks < 2; ++ks)
        vf[dt][ks] = *(const bf16x8*)&vb[(dt * 16 + qr) * 64 + (((ks * 4 + quad) ^ (qr & 7)) << 3)];

    bf16x8 pf[2][2];
#pragma unroll
    for (int mt = 0; mt < 2; ++mt)
#pragma unroll
      for (int ks = 0; ks < 2; ++ks)
        pf[mt][ks] =
            *(const bf16x8*)&pw[(mt * 16 + qr) * 64 + (((ks * 4 + quad) ^ (qr & 7)) << 3)];

#pragma unroll
    for (int mt = 0; mt < 2; ++mt) {
#pragma unroll
      for (int dt = 0; dt < 4; ++dt) {
        o[mt][dt] = MFMA16(pf[mt][0], vf[dt][0], o[mt][dt]);
        o[mt][dt] = MFMA16(pf[mt][1], vf[dt][1], o[mt][dt]);
      }
      l5[mt] = MFMA16(pf[mt][0], vone, l5[mt]);
      l5[mt] = MFMA16(pf[mt][1], vone, l5[mt]);
    }
  }

  // l5[mt][r] already holds the denominator for exactly the rows this lane stores.
  u16* obase = out + (size_t)(b * SEQ + m0 + wave * 32) * CH + h * 64;
#pragma unroll
  for (int mt = 0; mt < 2; ++mt)
#pragma unroll
    for (int r = 0; r < 4; ++r) {
      float inv = 1.0f / l5[mt][r];
#pragma unroll
      for (int dt = 0; dt < 4; ++dt)
        obase[(size_t)(mt * 16 + quad * 4 + r) * CH + dt * 16 + qr] = f2bf(o[mt][dt][r] * inv);
    }
}

extern "C" void kernel_launch(void* const* d_in, const int* in_sizes, int n_in,
                              void* d_out, int out_size, void* d_ws, size_t ws_size,
                              hipStream_t stream) {
  const float* x      = (const float*)d_in[0];
  const float* qkv_w  = (const float*)d_in[1];
  const float* qkv_b  = (const float*)d_in[2];
  const float* proj_w = (const float*)d_in[3];
  const float* proj_b = (const float*)d_in[4];
  float* out = (float*)d_out;

  char* w = (char*)d_ws;
  // ws layout (42 MB):
  //   qkv_bf : 4096x3072 bf16 = 25165824 B
  //   xb     : 4096x1024 bf16 =  8388608 B  (reused as attn_bf after gemm1)
  //   wprojt : 1024x1024 bf16 =  2097152 B
  //   wqkvt  : 3072x1024 bf16 (6 MB) region sized 8 MB, reused as vt (B,H,D,N)
  u16* qkv_bf = (u16*)w;
  u16* xb     = (u16*)(w + 25165824);
  u16* wprojt = (u16*)(w + 25165824 + 8388608);
  u16* wqkvt  = (u16*)(w + 25165824 + 8388608 + 2097152);
  u16* attn_bf = xb;
  u16* vt      = wqkvt;

  cast_x_kernel<<<4096, 256, 0, stream>>>(x, xb);
  tcast_kernel<<<dim3(48, 16), 256, 0, stream>>>(qkv_w, wqkvt, 1024, 3072);
  tcast_kernel<<<dim3(16, 16), 256, 0, stream>>>(proj_w, wprojt, 1024, 1024);
  // qkv = x @ qkv_w + b  (bf16 out; Q cols pre-scaled by log2e/8)
  gemm_kernel<4><<<dim3(24, 32), 256, 0, stream>>>(xb, wqkvt, qkv_b, qkv_bf, nullptr, 3072, 1024, 0);
  tv_kernel<<<dim3(32, 32), 256, 0, stream>>>(qkv_bf, vt);
  attn_kernel<<<dim3(32, 16), 256, 0, stream>>>(qkv_bf, vt, attn_bf);
  // out = attn @ proj_w + b (fp32); 64x128 tile -> 512 blocks
  gemm_kernel<2><<<dim3(8, 64), 256, 0, stream>>>(attn_bf, wprojt, proj_b, nullptr, out, 1024, 1024, 1);
}

// Round 8
// 204.946 us; speedup vs baseline: 1.5223x; 1.0398x over previous
//
#include <hip/hip_runtime.h>
#include <cstdint>
#include <cstddef>

typedef __bf16 bf16x8 __attribute__((ext_vector_type(8)));
typedef __bf16 bf16x2v __attribute__((ext_vector_type(2)));
typedef unsigned short u16;
typedef u16 u16x8v __attribute__((ext_vector_type(8)));
typedef float  f32x4  __attribute__((ext_vector_type(4)));
typedef unsigned int u32;

#define MFMA16(a, b, c) __builtin_amdgcn_mfma_f32_16x16x32_bf16((a), (b), (c), 0, 0, 0)
#define ASYNC16(g, l)                                                              \
  __builtin_amdgcn_global_load_lds(                                                \
      (const __attribute__((address_space(1))) unsigned int*)(g),                  \
      (__attribute__((address_space(3))) unsigned int*)(l), 16, 0, 0)

__device__ __forceinline__ u16 f2bf(float f) {
  unsigned u = __builtin_bit_cast(unsigned, f);
  u += 0x7fffu + ((u >> 16) & 1u);
  return (u16)(u >> 16);
}

// packed fp32x2 -> bf16x2 (RNE) via hardware cvt
__device__ __forceinline__ u32 cvt2(float a, float b) {
  bf16x2v t;
  t[0] = (__bf16)a;
  t[1] = (__bf16)b;
  return __builtin_bit_cast(u32, t);
}

#define SEQ 2048
#define CH  1024
#define NH  16
#define HD  64
// log2(e) / sqrt(64) folded into stored Q so softmax uses exp2
#define QSCALE 0.18033688011112042f

// ------------- fused prep: cast x + transpose-cast qkv_w + proj_w -------------
__global__ void __launch_bounds__(256) prep_kernel(const float* __restrict__ x,
                                                   const float* __restrict__ qkv_w,
                                                   const float* __restrict__ proj_w,
                                                   u16* __restrict__ xb,
                                                   u16* __restrict__ wqkvt,
                                                   u16* __restrict__ wprojt) {
  __shared__ u16 t[64][68];
  int bx = blockIdx.x;
  int tx = threadIdx.x;
  if (bx < 4096) {
    int i = bx * 256 + tx;
    float4 v = ((const float4*)x)[i];
    ushort4 o;
    o.x = f2bf(v.x); o.y = f2bf(v.y); o.z = f2bf(v.z); o.w = f2bf(v.w);
    ((ushort4*)xb)[i] = o;
    return;
  }
  const float* in; u16* out; int R, C, c0, r0;
  if (bx < 4096 + 768) {
    int i = bx - 4096;
    in = qkv_w; out = wqkvt; R = 1024; C = 3072;
    c0 = (i % 48) * 64; r0 = (i / 48) * 64;
  } else {
    int i = bx - 4864;
    in = proj_w; out = wprojt; R = 1024; C = 1024;
    c0 = (i % 16) * 64; r0 = (i / 16) * 64;
  }
  int rr = tx >> 6, cc = tx & 63;
#pragma unroll
  for (int i = 0; i < 16; ++i) {
    int r = i * 4 + rr;
    t[r][cc] = f2bf(in[(size_t)(r0 + r) * C + c0 + cc]);
  }
  __syncthreads();
#pragma unroll
  for (int i = 0; i < 16; ++i) {
    int r = i * 4 + rr;
    out[(size_t)(c0 + r) * R + r0 + cc] = t[cc][r];
  }
}

// ------------- transpose V slice of qkv (per b,h: (N x D) -> (D x N)) -------------
__global__ void __launch_bounds__(256) tv_kernel(const u16* __restrict__ qkv,
                                                 u16* __restrict__ vt) {
  __shared__ u16 t[64][68];
  int n0 = blockIdx.x * 64;
  int bh = blockIdx.y;
  int b = bh >> 4, h = bh & 15;
  int tx = threadIdx.x;
  int rr = tx >> 6, cc = tx & 63;
  const u16* src = qkv + (size_t)(b * SEQ) * 3072 + 2048 + h * 64;
#pragma unroll
  for (int i = 0; i < 16; ++i) {
    int n = i * 4 + rr;
    t[n][cc] = src[(size_t)(n0 + n) * 3072 + cc];
  }
  __syncthreads();
  u16* dst = vt + (size_t)bh * 64 * SEQ;
#pragma unroll
  for (int i = 0; i < 16; ++i) {
    int d = i * 4 + rr;
    dst[(size_t)d * SEQ + n0 + cc] = t[cc][d];
  }
}

// ------------- GEMM: C(MxN) = A(MxK,bf16) @ Bt(NxK,bf16)^T + bias -------------
// Tile: (MT*32) x 128. MT=4 -> 128x128 (qkv gemm), MT=2 -> 64x128 (proj).
// mode 0: write bf16, scale cols<1024 by QSCALE.  mode 1: write fp32.
template <int MT>
__global__ void __launch_bounds__(256) gemm_kernel(const u16* __restrict__ A,
                                                   const u16* __restrict__ Bt,
                                                   const float* __restrict__ bias,
                                                   u16* __restrict__ outb,
                                                   float* __restrict__ outf,
                                                   int N, int K, int mode) {
  constexpr int R = MT * 32;
  __shared__ alignas(16) u16 As[R * 32];
  __shared__ alignas(16) u16 Bs[128 * 32];
  int tid = threadIdx.x;
  int lane = tid & 63, wave = tid >> 6;
  int wm = wave >> 1, wn = wave & 1;
  int qr = lane & 15, quad = lane >> 4;
  size_t rowA = (size_t)blockIdx.y * R;
  size_t rowB = (size_t)blockIdx.x * 128;
  int r0 = tid >> 2, c0 = (tid & 3) << 3;

  const u16* a0 = A + (rowA + r0) * K + c0;
  const u16* b0 = Bt + (rowB + r0) * K + c0;
  size_t step64 = (size_t)64 * K;
  u16* lA = &As[r0 * 32 + c0];
  u16* lB = &Bs[r0 * 32 + c0];

  f32x4 acc[MT][4];
#pragma unroll
  for (int mt = 0; mt < MT; ++mt)
#pragma unroll
    for (int nt = 0; nt < 4; ++nt) acc[mt][nt] = (f32x4){0.f, 0.f, 0.f, 0.f};

  for (int k0 = 0; k0 < K; k0 += 32) {
#pragma unroll
    for (int i = 0; i < R / 64; ++i)
      ASYNC16(a0 + k0 + i * step64, lA + i * 64 * 32);
    ASYNC16(b0 + k0, lB);
    ASYNC16(b0 + k0 + step64, lB + 64 * 32);
    __syncthreads();
    bf16x8 af[MT], bfr[4];
#pragma unroll
    for (int mt = 0; mt < MT; ++mt)
      af[mt] = *(const bf16x8*)&As[(wm * (MT * 16) + mt * 16 + qr) * 32 + quad * 8];
#pragma unroll
    for (int nt = 0; nt < 4; ++nt)
      bfr[nt] = *(const bf16x8*)&Bs[(wn * 64 + nt * 16 + qr) * 32 + quad * 8];
#pragma unroll
    for (int mt = 0; mt < MT; ++mt)
#pragma unroll
      for (int nt = 0; nt < 4; ++nt)
        acc[mt][nt] = MFMA16(af[mt], bfr[nt], acc[mt][nt]);
    __syncthreads();
  }

#pragma unroll
  for (int nt = 0; nt < 4; ++nt) {
    int col = (int)rowB + wn * 64 + nt * 16 + qr;
    float bv = bias[col];
#pragma unroll
    for (int mt = 0; mt < MT; ++mt) {
      size_t row = rowA + wm * (MT * 16) + mt * 16 + quad * 4;
#pragma unroll
      for (int r = 0; r < 4; ++r) {
        float v = acc[mt][nt][r] + bv;
        if (mode == 0) {
          if (col < 1024) v *= QSCALE;
          outb[(row + r) * N + col] = f2bf(v);
        } else {
          outf[(row + r) * N + col] = v;
        }
      }
    }
  }
}

// ------------- flash attention v6: 128 Q rows/block, BK=128 keys per barrier -------------
// K-tile (128x64) + Vt-tile (64x128) DMA'd to LDS (global_load_lds 16B, chunk-XOR
// swizzle), double-buffered: 64KB. One barrier per 128 keys (16 total).
// Two 64-key sub-phases per staged tile share the wave-private P buffer (no barrier).
// QK^T transposed (A=K, B=Q): lane holds 4 consecutive key-scores of one Q row.
// Denominator on the MFMA pipe via B=ones.
__global__ void __launch_bounds__(256) attn_kernel(const u16* __restrict__ qkv,
                                                   const u16* __restrict__ vt,
                                                   u16* __restrict__ out) {
  __shared__ alignas(16) u16 kbuf[2][128 * 64];
  __shared__ alignas(16) u16 vbuf[2][64 * 128];
  __shared__ alignas(16) u16 pbuf[4][32 * 64];
  int bh = blockIdx.x;
  int b = bh >> 4, h = bh & 15;
  int m0 = blockIdx.y * 128;
  int tid = threadIdx.x;
  int lane = tid & 63, wave = tid >> 6;
  int qr = lane & 15, quad = lane >> 4;

  const u16* kbase = qkv + (size_t)(b * SEQ) * 3072 + 1024 + h * 64;  // K rows, stride 3072
  const u16* vtbase = vt + (size_t)bh * 64 * SEQ;                     // Vt rows, stride 2048
  u16* pw = &pbuf[wave][0];

  // K staging: 4 instrs/wave; rows wave*32 + i*8 + (lane>>3); chunk swizzle ^(row&7)
  int klr = lane >> 3;                       // row-within-8
  int kcs = (lane & 7) ^ klr;                // global chunk for LDS slot lane&7
  // V staging: 4 instrs/wave; rows wave*16 + i*4 + (lane>>4); 16 chunk16 slots/row

  // ---- Q fragments (32 rows per wave) ----
  const u16* qbase = qkv + (size_t)(b * SEQ + m0 + wave * 32) * 3072 + h * 64;
  bf16x8 qf[2][2];
#pragma unroll
  for (int mt = 0; mt < 2; ++mt)
#pragma unroll
    for (int ks = 0; ks < 2; ++ks)
      qf[mt][ks] = *(const bf16x8*)&qbase[(size_t)(mt * 16 + qr) * 3072 + ks * 32 + quad * 8];

  const bf16x8 vone = __builtin_bit_cast(bf16x8, (u16x8v)((u16)0x3F80));

  f32x4 o[2][4], l5[2];
#pragma unroll
  for (int mt = 0; mt < 2; ++mt) {
    l5[mt] = (f32x4){0.f, 0.f, 0.f, 0.f};
#pragma unroll
    for (int dt = 0; dt < 4; ++dt) o[mt][dt] = (f32x4){0.f, 0.f, 0.f, 0.f};
  }

  auto stage = [&](int buf, int n0) {
#pragma unroll
    for (int i = 0; i < 4; ++i) {
      int kr = wave * 32 + i * 8 + klr;
      ASYNC16(kbase + (size_t)(n0 + kr) * 3072 + kcs * 8,
              &kbuf[buf][(wave * 32 + i * 8) * 64 + lane * 8]);
    }
#pragma unroll
    for (int i = 0; i < 4; ++i) {
      int vr = wave * 16 + i * 4 + (lane >> 4);
      int vcs = ((lane & 7) ^ (vr & 7)) | (lane & 8);
      ASYNC16(vtbase + (size_t)vr * 2048 + n0 + vcs * 8,
              &vbuf[buf][(wave * 16 + i * 4) * 128 + lane * 8]);
    }
  };

  stage(0, 0);

  for (int t = 0; t < 16; ++t) {
    int cur = t & 1;
    __syncthreads();  // staging of buf[cur] complete; prev reads of buf[cur^1] done

    if (t + 1 < 16) stage(cur ^ 1, (t + 1) * 128);

#pragma unroll
    for (int sp = 0; sp < 2; ++sp) {
      const u16* kb = &kbuf[cur][sp * 64 * 64];
      const u16* vb = &vbuf[cur][0];

      // S^T = K.Q^T : lane holds m = qr, n = nt*16 + quad*4 + r (4 consecutive keys)
      bf16x8 kf[4][2];
#pragma unroll
      for (int nt = 0; nt < 4; ++nt)
#pragma unroll
        for (int ks = 0; ks < 2; ++ks)
          kf[nt][ks] =
              *(const bf16x8*)&kb[(nt * 16 + qr) * 64 + (((ks * 4 + quad) ^ (qr & 7)) << 3)];

#pragma unroll
      for (int mt = 0; mt < 2; ++mt)
#pragma unroll
        for (int nt = 0; nt < 4; ++nt) {
          f32x4 z = (f32x4){0.f, 0.f, 0.f, 0.f};
          z = MFMA16(kf[nt][0], qf[mt][0], z);
          z = MFMA16(kf[nt][1], qf[mt][1], z);
          float p0 = __builtin_amdgcn_exp2f(z[0]);
          float p1 = __builtin_amdgcn_exp2f(z[1]);
          float p2 = __builtin_amdgcn_exp2f(z[2]);
          float p3 = __builtin_amdgcn_exp2f(z[3]);
          uint2 pk;
          pk.x = cvt2(p0, p1);
          pk.y = cvt2(p2, p3);
          int nb = nt * 16 + quad * 4;
          int addr = (mt * 16 + qr) * 64 + ((((nb >> 3) ^ (qr & 7)) << 3) | (nb & 7));
          *(uint2*)&pw[addr] = pk;
        }

      bf16x8 vf[4][2];
#pragma unroll
      for (int dt = 0; dt < 4; ++dt)
#pragma unroll
        for (int ks = 0; ks < 2; ++ks)
          vf[dt][ks] = *(const bf16x8*)&vb[(dt * 16 + qr) * 128 +
                                           ((sp * 8 + ((ks * 4 + quad) ^ (qr & 7))) << 3)];

      bf16x8 pf[2][2];
#pragma unroll
      for (int mt = 0; mt < 2; ++mt)
#pragma unroll
        for (int ks = 0; ks < 2; ++ks)
          pf[mt][ks] =
              *(const bf16x8*)&pw[(mt * 16 + qr) * 64 + (((ks * 4 + quad) ^ (qr & 7)) << 3)];

#pragma unroll
      for (int mt = 0; mt < 2; ++mt) {
#pragma unroll
        for (int dt = 0; dt < 4; ++dt) {
          o[mt][dt] = MFMA16(pf[mt][0], vf[dt][0], o[mt][dt]);
          o[mt][dt] = MFMA16(pf[mt][1], vf[dt][1], o[mt][dt]);
        }
        l5[mt] = MFMA16(pf[mt][0], vone, l5[mt]);
        l5[mt] = MFMA16(pf[mt][1], vone, l5[mt]);
      }
    }
  }

  // l5[mt][r] already holds the denominator for exactly the rows this lane stores.
  u16* obase = out + (size_t)(b * SEQ + m0 + wave * 32) * CH + h * 64;
#pragma unroll
  for (int mt = 0; mt < 2; ++mt)
#pragma unroll
    for (int r = 0; r < 4; ++r) {
      float inv = 1.0f / l5[mt][r];
#pragma unroll
      for (int dt = 0; dt < 4; ++dt)
        obase[(size_t)(mt * 16 + quad * 4 + r) * CH + dt * 16 + qr] = f2bf(o[mt][dt][r] * inv);
    }
}

extern "C" void kernel_launch(void* const* d_in, const int* in_sizes, int n_in,
                              void* d_out, int out_size, void* d_ws, size_t ws_size,
                              hipStream_t stream) {
  const float* x      = (const float*)d_in[0];
  const float* qkv_w  = (const float*)d_in[1];
  const float* qkv_b  = (const float*)d_in[2];
  const float* proj_w = (const float*)d_in[3];
  const float* proj_b = (const float*)d_in[4];
  float* out = (float*)d_out;

  char* w = (char*)d_ws;
  // ws layout (42 MB):
  //   qkv_bf : 4096x3072 bf16 = 25165824 B
  //   xb     : 4096x1024 bf16 =  8388608 B  (reused as attn_bf after gemm1)
  //   wprojt : 1024x1024 bf16 =  2097152 B
  //   wqkvt  : 3072x1024 bf16 (6 MB) region sized 8 MB, reused as vt (B,H,D,N)
  u16* qkv_bf = (u16*)w;
  u16* xb     = (u16*)(w + 25165824);
  u16* wprojt = (u16*)(w + 25165824 + 8388608);
  u16* wqkvt  = (u16*)(w + 25165824 + 8388608 + 2097152);
  u16* attn_bf = xb;
  u16* vt      = wqkvt;

  prep_kernel<<<5120, 256, 0, stream>>>(x, qkv_w, proj_w, xb, wqkvt, wprojt);
  // qkv = x @ qkv_w + b  (bf16 out; Q cols pre-scaled by log2e/8)
  gemm_kernel<4><<<dim3(24, 32), 256, 0, stream>>>(xb, wqkvt, qkv_b, qkv_bf, nullptr, 3072, 1024, 0);
  tv_kernel<<<dim3(32, 32), 256, 0, stream>>>(qkv_bf, vt);
  attn_kernel<<<dim3(32, 16), 256, 0, stream>>>(qkv_bf, vt, attn_bf);
  // out = attn @ proj_w + b (fp32); 64x128 tile -> 512 blocks
  gemm_kernel<2><<<dim3(8, 64), 256, 0, stream>>>(attn_bf, wprojt, proj_b, nullptr, out, 1024, 1024, 1);
}

// Round 9
// 204.941 us; speedup vs baseline: 1.5223x; 1.0000x over previous
//
#include <hip/hip_runtime.h>
#include <cstdint>
#include <cstddef>

typedef __bf16 bf16x8 __attribute__((ext_vector_type(8)));
typedef __bf16 bf16x2v __attribute__((ext_vector_type(2)));
typedef unsigned short u16;
typedef u16 u16x8v __attribute__((ext_vector_type(8)));
typedef float  f32x4  __attribute__((ext_vector_type(4)));
typedef unsigned int u32;

#define MFMA16(a, b, c) __builtin_amdgcn_mfma_f32_16x16x32_bf16((a), (b), (c), 0, 0, 0)
#define ASYNC16(g, l)                                                              \
  __builtin_amdgcn_global_load_lds(                                                \
      (const __attribute__((address_space(1))) unsigned int*)(g),                  \
      (__attribute__((address_space(3))) unsigned int*)(l), 16, 0, 0)

__device__ __forceinline__ u16 f2bf(float f) {
  unsigned u = __builtin_bit_cast(unsigned, f);
  u += 0x7fffu + ((u >> 16) & 1u);
  return (u16)(u >> 16);
}

// packed fp32x2 -> bf16x2 (RNE) via hardware cvt
__device__ __forceinline__ u32 cvt2(float a, float b) {
  bf16x2v t;
  t[0] = (__bf16)a;
  t[1] = (__bf16)b;
  return __builtin_bit_cast(u32, t);
}

#define SEQ 2048
#define CH  1024
#define NH  16
#define HD  64
// log2(e) / sqrt(64) folded into stored Q so softmax uses exp2
#define QSCALE 0.18033688011112042f

// ------------- fused prep: cast x + transpose-cast qkv_w + proj_w -------------
__global__ void __launch_bounds__(256) prep_kernel(const float* __restrict__ x,
                                                   const float* __restrict__ qkv_w,
                                                   const float* __restrict__ proj_w,
                                                   u16* __restrict__ xb,
                                                   u16* __restrict__ wqkvt,
                                                   u16* __restrict__ wprojt) {
  __shared__ u16 t[64][68];
  int bx = blockIdx.x;
  int tx = threadIdx.x;
  if (bx < 4096) {
    int i = bx * 256 + tx;
    float4 v = ((const float4*)x)[i];
    ushort4 o;
    o.x = f2bf(v.x); o.y = f2bf(v.y); o.z = f2bf(v.z); o.w = f2bf(v.w);
    ((ushort4*)xb)[i] = o;
    return;
  }
  const float* in; u16* out; int R, C, c0, r0;
  if (bx < 4096 + 768) {
    int i = bx - 4096;
    in = qkv_w; out = wqkvt; R = 1024; C = 3072;
    c0 = (i % 48) * 64; r0 = (i / 48) * 64;
  } else {
    int i = bx - 4864;
    in = proj_w; out = wprojt; R = 1024; C = 1024;
    c0 = (i % 16) * 64; r0 = (i / 16) * 64;
  }
  int rr = tx >> 6, cc = tx & 63;
#pragma unroll
  for (int i = 0; i < 16; ++i) {
    int r = i * 4 + rr;
    t[r][cc] = f2bf(in[(size_t)(r0 + r) * C + c0 + cc]);
  }
  __syncthreads();
#pragma unroll
  for (int i = 0; i < 16; ++i) {
    int r = i * 4 + rr;
    out[(size_t)(c0 + r) * R + r0 + cc] = t[cc][r];
  }
}

// ------------- transpose V slice of qkv (per b,h: (N x D) -> (D x N)) -------------
__global__ void __launch_bounds__(256) tv_kernel(const u16* __restrict__ qkv,
                                                 u16* __restrict__ vt) {
  __shared__ u16 t[64][68];
  int n0 = blockIdx.x * 64;
  int bh = blockIdx.y;
  int b = bh >> 4, h = bh & 15;
  int tx = threadIdx.x;
  int rr = tx >> 6, cc = tx & 63;
  const u16* src = qkv + (size_t)(b * SEQ) * 3072 + 2048 + h * 64;
#pragma unroll
  for (int i = 0; i < 16; ++i) {
    int n = i * 4 + rr;
    t[n][cc] = src[(size_t)(n0 + n) * 3072 + cc];
  }
  __syncthreads();
  u16* dst = vt + (size_t)bh * 64 * SEQ;
#pragma unroll
  for (int i = 0; i < 16; ++i) {
    int d = i * 4 + rr;
    dst[(size_t)d * SEQ + n0 + cc] = t[cc][d];
  }
}

// ------------- GEMM: C(MxN) = A(MxK,bf16) @ Bt(NxK,bf16)^T + bias -------------
// Tile: (MT*32) x 128. MT=4 -> 128x128 (qkv gemm), MT=2 -> 64x128 (proj).
// mode 0: write bf16, scale cols<1024 by QSCALE.  mode 1: write fp32.
template <int MT>
__global__ void __launch_bounds__(256) gemm_kernel(const u16* __restrict__ A,
                                                   const u16* __restrict__ Bt,
                                                   const float* __restrict__ bias,
                                                   u16* __restrict__ outb,
                                                   float* __restrict__ outf,
                                                   int N, int K, int mode) {
  constexpr int R = MT * 32;
  __shared__ alignas(16) u16 As[R * 32];
  __shared__ alignas(16) u16 Bs[128 * 32];
  int tid = threadIdx.x;
  int lane = tid & 63, wave = tid >> 6;
  int wm = wave >> 1, wn = wave & 1;
  int qr = lane & 15, quad = lane >> 4;
  size_t rowA = (size_t)blockIdx.y * R;
  size_t rowB = (size_t)blockIdx.x * 128;
  int r0 = tid >> 2, c0 = (tid & 3) << 3;

  const u16* a0 = A + (rowA + r0) * K + c0;
  const u16* b0 = Bt + (rowB + r0) * K + c0;
  size_t step64 = (size_t)64 * K;
  u16* lA = &As[r0 * 32 + c0];
  u16* lB = &Bs[r0 * 32 + c0];

  f32x4 acc[MT][4];
#pragma unroll
  for (int mt = 0; mt < MT; ++mt)
#pragma unroll
    for (int nt = 0; nt < 4; ++nt) acc[mt][nt] = (f32x4){0.f, 0.f, 0.f, 0.f};

  for (int k0 = 0; k0 < K; k0 += 32) {
#pragma unroll
    for (int i = 0; i < R / 64; ++i)
      ASYNC16(a0 + k0 + i * step64, lA + i * 64 * 32);
    ASYNC16(b0 + k0, lB);
    ASYNC16(b0 + k0 + step64, lB + 64 * 32);
    __syncthreads();
    bf16x8 af[MT], bfr[4];
#pragma unroll
    for (int mt = 0; mt < MT; ++mt)
      af[mt] = *(const bf16x8*)&As[(wm * (MT * 16) + mt * 16 + qr) * 32 + quad * 8];
#pragma unroll
    for (int nt = 0; nt < 4; ++nt)
      bfr[nt] = *(const bf16x8*)&Bs[(wn * 64 + nt * 16 + qr) * 32 + quad * 8];
#pragma unroll
    for (int mt = 0; mt < MT; ++mt)
#pragma unroll
      for (int nt = 0; nt < 4; ++nt)
        acc[mt][nt] = MFMA16(af[mt], bfr[nt], acc[mt][nt]);
    __syncthreads();
  }

#pragma unroll
  for (int nt = 0; nt < 4; ++nt) {
    int col = (int)rowB + wn * 64 + nt * 16 + qr;
    float bv = bias[col];
#pragma unroll
    for (int mt = 0; mt < MT; ++mt) {
      size_t row = rowA + wm * (MT * 16) + mt * 16 + quad * 4;
#pragma unroll
      for (int r = 0; r < 4; ++r) {
        float v = acc[mt][nt][r] + bv;
        if (mode == 0) {
          if (col < 1024) v *= QSCALE;
          outb[(row + r) * N + col] = f2bf(v);
        } else {
          outf[(row + r) * N + col] = v;
        }
      }
    }
  }
}

// ------------- flash attention v7: 256 Q rows/block, 4 waves x 64 rows -------------
// LDS-bound fix: 64 rows/wave halves K/V LDS reads per Q-row (16 b128 serve 64 MFMA).
// K-tile (128x64) + Vt-tile (64x128) DMA'd to LDS, double-buffered; BK=128 keys per
// barrier (16 barriers). Two 64-key sub-phases per staged tile share wave-private P.
// QK^T transposed (A=K, B=Q); denominator on the MFMA pipe via B=ones.
// Grid 256 = 1 block/CU; DMA prefetch covers global latency, ILP covers the rest.
__global__ void __launch_bounds__(256) attn_kernel(const u16* __restrict__ qkv,
                                                   const u16* __restrict__ vt,
                                                   u16* __restrict__ out) {
  __shared__ alignas(16) u16 kbuf[2][128 * 64];
  __shared__ alignas(16) u16 vbuf[2][64 * 128];
  __shared__ alignas(16) u16 pbuf[4][64 * 64];
  int bh = blockIdx.x;
  int b = bh >> 4, h = bh & 15;
  int m0 = blockIdx.y * 256;
  int tid = threadIdx.x;
  int lane = tid & 63, wave = tid >> 6;
  int qr = lane & 15, quad = lane >> 4;

  const u16* kbase = qkv + (size_t)(b * SEQ) * 3072 + 1024 + h * 64;  // K rows, stride 3072
  const u16* vtbase = vt + (size_t)bh * 64 * SEQ;                     // Vt rows, stride 2048
  u16* pw = &pbuf[wave][0];

  // K staging: 4 instrs/wave; rows wave*32 + i*8 + (lane>>3); chunk swizzle ^(row&7)
  int klr = lane >> 3;
  int kcs = (lane & 7) ^ klr;

  // ---- Q fragments (64 rows per wave) ----
  const u16* qbase = qkv + (size_t)(b * SEQ + m0 + wave * 64) * 3072 + h * 64;
  bf16x8 qf[4][2];
#pragma unroll
  for (int mt = 0; mt < 4; ++mt)
#pragma unroll
    for (int ks = 0; ks < 2; ++ks)
      qf[mt][ks] = *(const bf16x8*)&qbase[(size_t)(mt * 16 + qr) * 3072 + ks * 32 + quad * 8];

  const bf16x8 vone = __builtin_bit_cast(bf16x8, (u16x8v)((u16)0x3F80));

  f32x4 o[4][4], l5[4];
#pragma unroll
  for (int mt = 0; mt < 4; ++mt) {
    l5[mt] = (f32x4){0.f, 0.f, 0.f, 0.f};
#pragma unroll
    for (int dt = 0; dt < 4; ++dt) o[mt][dt] = (f32x4){0.f, 0.f, 0.f, 0.f};
  }

  auto stage = [&](int buf, int n0) {
#pragma unroll
    for (int i = 0; i < 4; ++i) {
      int kr = wave * 32 + i * 8 + klr;
      ASYNC16(kbase + (size_t)(n0 + kr) * 3072 + kcs * 8,
              &kbuf[buf][(wave * 32 + i * 8) * 64 + lane * 8]);
    }
#pragma unroll
    for (int i = 0; i < 4; ++i) {
      int vr = wave * 16 + i * 4 + (lane >> 4);
      int vcs = ((lane & 7) ^ (vr & 7)) | (lane & 8);
      ASYNC16(vtbase + (size_t)vr * 2048 + n0 + vcs * 8,
              &vbuf[buf][(wave * 16 + i * 4) * 128 + lane * 8]);
    }
  };

  stage(0, 0);

  for (int t = 0; t < 16; ++t) {
    int cur = t & 1;
    __syncthreads();  // staging of buf[cur] complete; prev reads of buf[cur^1] done

    if (t + 1 < 16) stage(cur ^ 1, (t + 1) * 128);

#pragma unroll
    for (int sp = 0; sp < 2; ++sp) {
      const u16* kb = &kbuf[cur][sp * 64 * 64];
      const u16* vb = &vbuf[cur][0];

      // S^T = K.Q^T : lane holds m = qr, n = nt*16 + quad*4 + r (4 consecutive keys)
      bf16x8 kf[4][2];
#pragma unroll
      for (int nt = 0; nt < 4; ++nt)
#pragma unroll
        for (int ks = 0; ks < 2; ++ks)
          kf[nt][ks] =
              *(const bf16x8*)&kb[(nt * 16 + qr) * 64 + (((ks * 4 + quad) ^ (qr & 7)) << 3)];

#pragma unroll
      for (int mt = 0; mt < 4; ++mt)
#pragma unroll
        for (int nt = 0; nt < 4; ++nt) {
          f32x4 z = (f32x4){0.f, 0.f, 0.f, 0.f};
          z = MFMA16(kf[nt][0], qf[mt][0], z);
          z = MFMA16(kf[nt][1], qf[mt][1], z);
          float p0 = __builtin_amdgcn_exp2f(z[0]);
          float p1 = __builtin_amdgcn_exp2f(z[1]);
          float p2 = __builtin_amdgcn_exp2f(z[2]);
          float p3 = __builtin_amdgcn_exp2f(z[3]);
          uint2 pk;
          pk.x = cvt2(p0, p1);
          pk.y = cvt2(p2, p3);
          int nb = nt * 16 + quad * 4;
          int addr = (mt * 16 + qr) * 64 + ((((nb >> 3) ^ (qr & 7)) << 3) | (nb & 7));
          *(uint2*)&pw[addr] = pk;
        }

      bf16x8 vf[4][2];
#pragma unroll
      for (int dt = 0; dt < 4; ++dt)
#pragma unroll
        for (int ks = 0; ks < 2; ++ks)
          vf[dt][ks] = *(const bf16x8*)&vb[(dt * 16 + qr) * 128 +
                                           ((sp * 8 + ((ks * 4 + quad) ^ (qr & 7))) << 3)];

      bf16x8 pf[4][2];
#pragma unroll
      for (int mt = 0; mt < 4; ++mt)
#pragma unroll
        for (int ks = 0; ks < 2; ++ks)
          pf[mt][ks] =
              *(const bf16x8*)&pw[(mt * 16 + qr) * 64 + (((ks * 4 + quad) ^ (qr & 7)) << 3)];

#pragma unroll
      for (int mt = 0; mt < 4; ++mt) {
#pragma unroll
        for (int dt = 0; dt < 4; ++dt) {
          o[mt][dt] = MFMA16(pf[mt][0], vf[dt][0], o[mt][dt]);
          o[mt][dt] = MFMA16(pf[mt][1], vf[dt][1], o[mt][dt]);
        }
        l5[mt] = MFMA16(pf[mt][0], vone, l5[mt]);
        l5[mt] = MFMA16(pf[mt][1], vone, l5[mt]);
      }
    }
  }

  // l5[mt][r] already holds the denominator for exactly the rows this lane stores.
  u16* obase = out + (size_t)(b * SEQ + m0 + wave * 64) * CH + h * 64;
#pragma unroll
  for (int mt = 0; mt < 4; ++mt)
#pragma unroll
    for (int r = 0; r < 4; ++r) {
      float inv = 1.0f / l5[mt][r];
#pragma unroll
      for (int dt = 0; dt < 4; ++dt)
        obase[(size_t)(mt * 16 + quad * 4 + r) * CH + dt * 16 + qr] = f2bf(o[mt][dt][r] * inv);
    }
}

extern "C" void kernel_launch(void* const* d_in, const int* in_sizes, int n_in,
                              void* d_out, int out_size, void* d_ws, size_t ws_size,
                              hipStream_t stream) {
  const float* x      = (const float*)d_in[0];
  const float* qkv_w  = (const float*)d_in[1];
  const float* qkv_b  = (const float*)d_in[2];
  const float* proj_w = (const float*)d_in[3];
  const float* proj_b = (const float*)d_in[4];
  float* out = (float*)d_out;

  char* w = (char*)d_ws;
  // ws layout (42 MB):
  //   qkv_bf : 4096x3072 bf16 = 25165824 B
  //   xb     : 4096x1024 bf16 =  8388608 B  (reused as attn_bf after gemm1)
  //   wprojt : 1024x1024 bf16 =  2097152 B
  //   wqkvt  : 3072x1024 bf16 (6 MB) region sized 8 MB, reused as vt (B,H,D,N)
  u16* qkv_bf = (u16*)w;
  u16* xb     = (u16*)(w + 25165824);
  u16* wprojt = (u16*)(w + 25165824 + 8388608);
  u16* wqkvt  = (u16*)(w + 25165824 + 8388608 + 2097152);
  u16* attn_bf = xb;
  u16* vt      = wqkvt;

  prep_kernel<<<5120, 256, 0, stream>>>(x, qkv_w, proj_w, xb, wqkvt, wprojt);
  // qkv = x @ qkv_w + b  (bf16 out; Q cols pre-scaled by log2e/8)
  gemm_kernel<4><<<dim3(24, 32), 256, 0, stream>>>(xb, wqkvt, qkv_b, qkv_bf, nullptr, 3072, 1024, 0);
  tv_kernel<<<dim3(32, 32), 256, 0, stream>>>(qkv_bf, vt);
  attn_kernel<<<dim3(32, 8), 256, 0, stream>>>(qkv_bf, vt, attn_bf);
  // out = attn @ proj_w + b (fp32); 64x128 tile -> 512 blocks
  gemm_kernel<2><<<dim3(8, 64), 256, 0, stream>>>(attn_bf, wprojt, proj_b, nullptr, out, 1024, 1024, 1);
}